// Round 9
// baseline (1025.350 us; speedup 1.0000x reference)
//
#include <hip/hip_runtime.h>

// ---------------------------------------------------------------------------
// HeteroSAGE: CSR pull with XCD-local (L2-scope) atomic CSR build.
//   count8: per-XCD private histograms (workgroup-scope atomics -> local TCC)
//   scan8:  sum 8 copies + chunked exclusive scan -> cnt, rs, rn
//   fill_q: dst-windowed fill; window pinned to its XCD via s_getreg(XCC_ID),
//           chunk queue for coverage; rn atomics + csr stores stay in one L2.
//   proj (h bf16 + root f32) -> pull (8 waves/EU, unroll-4 gathers) -> pull2.
// ---------------------------------------------------------------------------

typedef unsigned short ushort_t;

#define WBITS 15      // 32768-dst windows: csr window ~2MB in one XCD L2
#define FCHUNK 8192   // edges per queue-grab in fill_q

__device__ inline ushort_t f2bf(float f) {
    unsigned u = __float_as_uint(f);
    unsigned r = (u + 0x7FFFu + ((u >> 16) & 1u)) >> 16;
    return (ushort_t)r;
}
__device__ inline float bf2f_lo(unsigned u) { return __uint_as_float(u << 16); }
__device__ inline float bf2f_hi(unsigned u) { return __uint_as_float(u & 0xFFFF0000u); }
__device__ inline int ntl(const int* p) { return __builtin_nontemporal_load(p); }

__device__ inline int xcc_id() {
    int x;
    asm volatile("s_getreg_b32 %0, hwreg(HW_REG_XCC_ID)" : "=s"(x));
    return x & 7;
}
__device__ inline void l2_add(int* p) {
    __hip_atomic_fetch_add(p, 1, __ATOMIC_RELAXED, __HIP_MEMORY_SCOPE_WORKGROUP);
}
__device__ inline int l2_add_ret(int* p) {
    return __hip_atomic_fetch_add(p, 1, __ATOMIC_RELAXED, __HIP_MEMORY_SCOPE_WORKGROUP);
}

__global__ void prep_weights(
    const float* __restrict__ Wl1_pp, const float* __restrict__ Wr1_pp,
    const float* __restrict__ Wl1_ap, const float* __restrict__ Wr1_ap,
    const float* __restrict__ Wl1_pa, const float* __restrict__ Wr1_pa,
    const float* __restrict__ bl1_pp, const float* __restrict__ bl1_ap,
    const float* __restrict__ bl1_pa,
    const float* __restrict__ Wl2_pp, const float* __restrict__ bl2_pp,
    const float* __restrict__ Wr2_pp,
    const float* __restrict__ Wl2_ap, const float* __restrict__ bl2_ap,
    const float* __restrict__ Wr2_ap,
    const float* __restrict__ W_lin, const float* __restrict__ b_lin,
    float* __restrict__ Wcomb_p,  // 64 x 96: [Wl1_pp | Wl1_pa | Wr1_pp+Wr1_ap]
    float* __restrict__ Wcomb_a,  // 64 x 64: [Wl1_ap | Wr1_pa]
    float* __restrict__ bias_p,   // 32
    float* __restrict__ bias_a,   // 32
    float* __restrict__ vv)       // [0:32) v_pp  [32:64) v_r  [64] c2  [96:128) v_ap
{
    int t = threadIdx.x;
    for (int idx = t; idx < 64 * 96; idx += 256) {
        int i = idx / 96, j = idx % 96;
        float v;
        if (j < 32)       v = Wl1_pp[i * 32 + j];
        else if (j < 64)  v = Wl1_pa[i * 32 + (j - 32)];
        else              v = Wr1_pp[i * 32 + (j - 64)] + Wr1_ap[i * 32 + (j - 64)];
        Wcomb_p[idx] = v;
    }
    for (int idx = t; idx < 64 * 64; idx += 256) {
        int i = idx / 64, j = idx % 64;
        Wcomb_a[idx] = (j < 32) ? Wl1_ap[i * 32 + j] : Wr1_pa[i * 32 + (j - 32)];
    }
    if (t < 32) {
        bias_p[t] = bl1_pp[t] + bl1_ap[t];
        bias_a[t] = bl1_pa[t];
        float vpp = 0.f, vr = 0.f, vap = 0.f;
        for (int j = 0; j < 32; ++j) {
            float wl = W_lin[j];
            vpp += Wl2_pp[t * 32 + j] * wl;
            vr  += (Wr2_pp[t * 32 + j] + Wr2_ap[t * 32 + j]) * wl;
            vap += Wl2_ap[t * 32 + j] * wl;
        }
        vv[t] = vpp; vv[32 + t] = vr; vv[96 + t] = vap;
    }
    if (t == 0) {
        float c = b_lin[0];
        for (int j = 0; j < 32; ++j) c += (bl2_pp[j] + bl2_ap[j]) * W_lin[j];
        vv[64] = c;
    }
}

// per-XCD private histograms: all atomics are local-L2 (workgroup scope),
// correctness holds because copy x is only touched by blocks on XCD x.
__global__ void count8(const int* __restrict__ d0, int E0,
                       const int* __restrict__ d1, int E1,
                       const int* __restrict__ d2, int E2,
                       int* __restrict__ cnt8, int S, int NP)
{
    int* base = cnt8 + (size_t)xcc_id() * S;
    int t = blockIdx.x * blockDim.x + threadIdx.x;
    int stride = gridDim.x * blockDim.x;
    for (int e = t; e < E0; e += stride) l2_add(&base[ntl(d0 + e)]);
    int* b1 = base + NP;
    for (int e = t; e < E1; e += stride) l2_add(&b1[ntl(d1 + e)]);
    int* b2 = base + 2 * NP;
    for (int e = t; e < E2; e += stride) l2_add(&b2[ntl(d2 + e)]);
}

// sum the 8 private copies + chunked exclusive scan; writes cnt, rs, rn(=rs).
__global__ void scan8(const int* __restrict__ cnt8, int S,
                      int* __restrict__ cnt, int* __restrict__ rs,
                      int* __restrict__ rn, int* __restrict__ total, int N)
{
    __shared__ int wsum[4];
    __shared__ int bbase;
    int base = blockIdx.x * 2048 + threadIdx.x * 8;
    int v[8]; int ts = 0;
#pragma unroll
    for (int k = 0; k < 8; ++k) {
        int idx = base + k;
        int s = 0;
        if (idx < N) {
#pragma unroll
            for (int x = 0; x < 8; ++x) s += cnt8[(size_t)x * S + idx];
            cnt[idx] = s;
        }
        v[k] = s;
        ts += s;
    }
    int lane = threadIdx.x & 63;
    int incl = ts;
#pragma unroll
    for (int off = 1; off < 64; off <<= 1) {
        int o = __shfl_up(incl, off);
        if (lane >= off) incl += o;
    }
    int wid = threadIdx.x >> 6;
    if (lane == 63) wsum[wid] = incl;
    __syncthreads();
    int btot = wsum[0] + wsum[1] + wsum[2] + wsum[3];
    if (threadIdx.x == 0) bbase = atomicAdd(total, btot);
    int woff = 0;
    for (int w = 0; w < 4; ++w) if (w < wid) woff += wsum[w];
    __syncthreads();
    int run = bbase + woff + (incl - ts);
#pragma unroll
    for (int k = 0; k < 8; ++k) {
        int idx = base + k;
        if (idx < N) { rs[idx] = run; rn[idx] = run; }
        run += v[k];
    }
}

// dst-windowed fill; window w handled ONLY by blocks whose real XCC_ID == w&7,
// with a device-scope chunk queue for coverage. rn atomics + csr stores are
// then XCD-local -> L2-executed atomics, full-line csr accumulation.
__global__ void fill_q(
    const int* __restrict__ src0, const int* __restrict__ dst0,
    int* __restrict__ rn0, int* __restrict__ csr0, int E0, int np0,
    const int* __restrict__ src1, const int* __restrict__ dst1,
    int* __restrict__ rn1, int* __restrict__ csr1, int E1, int np1,
    const int* __restrict__ src2, const int* __restrict__ dst2,
    int* __restrict__ rn2, int* __restrict__ csr2, int E2, int np2,
    int* __restrict__ queue)
{
    __shared__ int sh;
    int xcd = xcc_id();
    int nwin = np0 + np1 + np2;
    for (int w = 0; w < nwin; ++w) {
        if ((w & 7) != xcd) continue;
        const int* src; const int* dst; int* rn; int* csr; int E; int pass;
        if (w < np0)            { src = src0; dst = dst0; rn = rn0; csr = csr0; E = E0; pass = w; }
        else if (w < np0 + np1) { src = src1; dst = dst1; rn = rn1; csr = csr1; E = E1; pass = w - np0; }
        else                    { src = src2; dst = dst2; rn = rn2; csr = csr2; E = E2; pass = w - np0 - np1; }
        while (true) {
            if (threadIdx.x == 0) sh = atomicAdd(&queue[w], 1);
            __syncthreads();
            int c = sh;
            __syncthreads();
            int e0 = c * FCHUNK;
            if (e0 >= E) break;
            int e1 = e0 + FCHUNK; if (e1 > E) e1 = E;
            for (int e = e0 + threadIdx.x; e < e1; e += 256) {
                int d = ntl(dst + e);
                if ((d >> WBITS) == pass) {
                    int pos = l2_add_ret(&rn[d]);
                    csr[pos] = ntl(src + e);
                }
            }
        }
    }
}

// paper projection: h_pp, h_pa (bf16 neighbor features) + root_p (f32, incl bias)
__global__ void proj_paper(const float* __restrict__ x, const float* __restrict__ Wc,
                           const float* __restrict__ bias,
                           ushort_t* __restrict__ h_pp, ushort_t* __restrict__ h_pa,
                           float* __restrict__ root_p, int N)
{
    __shared__ float Wlds[64 * 96];
    __shared__ float blds[32];
    for (int i = threadIdx.x; i < 64 * 96; i += 256) Wlds[i] = Wc[i];
    if (threadIdx.x < 32) blds[threadIdx.x] = bias[threadIdx.x];
    __syncthreads();
    int n = blockIdx.x * 8 + (threadIdx.x >> 5);
    int c = threadIdx.x & 31;
    if (n < N) {
        const float* xr = x + (size_t)n * 64;
        float a0 = 0.f, a1 = 0.f, a2 = 0.f;
#pragma unroll
        for (int i = 0; i < 64; ++i) {
            float xv = xr[i];
            a0 += xv * Wlds[i * 96 + c];
            a1 += xv * Wlds[i * 96 + 32 + c];
            a2 += xv * Wlds[i * 96 + 64 + c];
        }
        h_pp[(size_t)n * 32 + c] = f2bf(a0);
        h_pa[(size_t)n * 32 + c] = f2bf(a1);
        root_p[(size_t)n * 32 + c] = a2 + blds[c];
    }
}

__global__ void proj_author(const float* __restrict__ x, const float* __restrict__ Wc,
                            const float* __restrict__ bias,
                            ushort_t* __restrict__ h_ap, float* __restrict__ root_a, int N)
{
    __shared__ float Wlds[64 * 64];
    __shared__ float blds[32];
    for (int i = threadIdx.x; i < 64 * 64; i += 256) Wlds[i] = Wc[i];
    if (threadIdx.x < 32) blds[threadIdx.x] = bias[threadIdx.x];
    __syncthreads();
    int n = blockIdx.x * 8 + (threadIdx.x >> 5);
    int c = threadIdx.x & 31;
    if (n < N) {
        const float* xr = x + (size_t)n * 64;
        float a0 = 0.f, a1 = 0.f;
#pragma unroll
        for (int i = 0; i < 64; ++i) {
            float xv = xr[i];
            a0 += xv * Wlds[i * 64 + c];
            a1 += xv * Wlds[i * 64 + 32 + c];
        }
        h_ap[(size_t)n * 32 + c] = f2bf(a0);
        root_a[(size_t)n * 32 + c] = a1 + blds[c];
    }
}

// 16 lanes/node, 2 cols/lane, tiny LDS, high occupancy. Unroll-4 independent
// gathers; fuses mean + root + relu + layer-2 dot products.
__global__ __launch_bounds__(256, 8)
void pull_paper(const ushort_t* __restrict__ h_pp, const ushort_t* __restrict__ h_ap,
                const float* __restrict__ root,
                const int* __restrict__ csr_pp, const int* __restrict__ rs_pp,
                const int* __restrict__ cnt_pp,
                const int* __restrict__ csr_ap, const int* __restrict__ rs_ap,
                const int* __restrict__ cnt_ap,
                const float* __restrict__ vv,
                float* __restrict__ s_pp, float* __restrict__ out, int N)
{
    __shared__ float v0[32], v1[32];
    __shared__ float c2s;
    if (threadIdx.x < 32) { v0[threadIdx.x] = vv[threadIdx.x]; v1[threadIdx.x] = vv[32 + threadIdx.x]; }
    if (threadIdx.x == 0) c2s = vv[64];
    __syncthreads();
    int n = blockIdx.x * 16 + (threadIdx.x >> 4);
    if (n >= N) return;
    int c = threadIdx.x & 15;
    const ushort_t* hpp_c = h_pp + 2 * c;
    const ushort_t* hap_c = h_ap + 2 * c;
    int s1 = rs_pp[n], k1 = cnt_pp[n], e1 = s1 + k1;
    float a0 = 0.f, a1 = 0.f;
    int j = s1;
    for (; j + 4 <= e1; j += 4) {
        int i0 = ntl(csr_pp + j), i1 = ntl(csr_pp + j + 1);
        int i2 = ntl(csr_pp + j + 2), i3 = ntl(csr_pp + j + 3);
        unsigned u0 = *(const unsigned*)(hpp_c + (size_t)i0 * 32);
        unsigned u1 = *(const unsigned*)(hpp_c + (size_t)i1 * 32);
        unsigned u2 = *(const unsigned*)(hpp_c + (size_t)i2 * 32);
        unsigned u3 = *(const unsigned*)(hpp_c + (size_t)i3 * 32);
        a0 += (bf2f_lo(u0) + bf2f_lo(u1)) + (bf2f_lo(u2) + bf2f_lo(u3));
        a1 += (bf2f_hi(u0) + bf2f_hi(u1)) + (bf2f_hi(u2) + bf2f_hi(u3));
    }
    for (; j < e1; ++j) {
        unsigned u0 = *(const unsigned*)(hpp_c + (size_t)ntl(csr_pp + j) * 32);
        a0 += bf2f_lo(u0); a1 += bf2f_hi(u0);
    }
    int s2 = rs_ap[n], k2 = cnt_ap[n], e2 = s2 + k2;
    float b0 = 0.f, b1 = 0.f;
    j = s2;
    for (; j + 4 <= e2; j += 4) {
        int i0 = ntl(csr_ap + j), i1 = ntl(csr_ap + j + 1);
        int i2 = ntl(csr_ap + j + 2), i3 = ntl(csr_ap + j + 3);
        unsigned u0 = *(const unsigned*)(hap_c + (size_t)i0 * 32);
        unsigned u1 = *(const unsigned*)(hap_c + (size_t)i1 * 32);
        unsigned u2 = *(const unsigned*)(hap_c + (size_t)i2 * 32);
        unsigned u3 = *(const unsigned*)(hap_c + (size_t)i3 * 32);
        b0 += (bf2f_lo(u0) + bf2f_lo(u1)) + (bf2f_lo(u2) + bf2f_lo(u3));
        b1 += (bf2f_hi(u0) + bf2f_hi(u1)) + (bf2f_hi(u2) + bf2f_hi(u3));
    }
    for (; j < e2; ++j) {
        unsigned u0 = *(const unsigned*)(hap_c + (size_t)ntl(csr_ap + j) * 32);
        b0 += bf2f_lo(u0); b1 += bf2f_hi(u0);
    }
    float ipp = 1.0f / fmaxf((float)k1, 1.0f);
    float iap = 1.0f / fmaxf((float)k2, 1.0f);
    float p0 = fmaxf(root[(size_t)n * 32 + 2 * c]     + a0 * ipp + b0 * iap, 0.f);
    float p1 = fmaxf(root[(size_t)n * 32 + 2 * c + 1] + a1 * ipp + b1 * iap, 0.f);
    float d0 = p0 * v0[2 * c] + p1 * v0[2 * c + 1];
    float d1 = p0 * v1[2 * c] + p1 * v1[2 * c + 1];
#pragma unroll
    for (int off = 1; off < 16; off <<= 1) {
        d0 += __shfl_xor(d0, off);
        d1 += __shfl_xor(d1, off);
    }
    if (c == 0) { s_pp[n] = d0; out[n] = d1 + c2s; }
}

__global__ __launch_bounds__(256, 8)
void pull_author(const ushort_t* __restrict__ h_pa, const float* __restrict__ root,
                 const int* __restrict__ csr_pa, const int* __restrict__ rs_pa,
                 const int* __restrict__ cnt_pa,
                 const float* __restrict__ vv, float* __restrict__ s_ap, int N)
{
    __shared__ float v0[32];
    if (threadIdx.x < 32) v0[threadIdx.x] = vv[96 + threadIdx.x];
    __syncthreads();
    int n = blockIdx.x * 16 + (threadIdx.x >> 4);
    if (n >= N) return;
    int c = threadIdx.x & 15;
    const ushort_t* hpa_c = h_pa + 2 * c;
    int s1 = rs_pa[n], k1 = cnt_pa[n], e1 = s1 + k1;
    float a0 = 0.f, a1 = 0.f;
    int j = s1;
    for (; j + 4 <= e1; j += 4) {
        int i0 = ntl(csr_pa + j), i1 = ntl(csr_pa + j + 1);
        int i2 = ntl(csr_pa + j + 2), i3 = ntl(csr_pa + j + 3);
        unsigned u0 = *(const unsigned*)(hpa_c + (size_t)i0 * 32);
        unsigned u1 = *(const unsigned*)(hpa_c + (size_t)i1 * 32);
        unsigned u2 = *(const unsigned*)(hpa_c + (size_t)i2 * 32);
        unsigned u3 = *(const unsigned*)(hpa_c + (size_t)i3 * 32);
        a0 += (bf2f_lo(u0) + bf2f_lo(u1)) + (bf2f_lo(u2) + bf2f_lo(u3));
        a1 += (bf2f_hi(u0) + bf2f_hi(u1)) + (bf2f_hi(u2) + bf2f_hi(u3));
    }
    for (; j < e1; ++j) {
        unsigned u0 = *(const unsigned*)(hpa_c + (size_t)ntl(csr_pa + j) * 32);
        a0 += bf2f_lo(u0); a1 += bf2f_hi(u0);
    }
    float ip = 1.0f / fmaxf((float)k1, 1.0f);
    float p0 = fmaxf(root[(size_t)n * 32 + 2 * c]     + a0 * ip, 0.f);
    float p1 = fmaxf(root[(size_t)n * 32 + 2 * c + 1] + a1 * ip, 0.f);
    float d0 = p0 * v0[2 * c] + p1 * v0[2 * c + 1];
#pragma unroll
    for (int off = 1; off < 16; off <<= 1) d0 += __shfl_xor(d0, off);
    if (c == 0) s_ap[n] = d0;
}

// layer-2 scalar pull, 4 lanes/node.
__global__ __launch_bounds__(256, 8)
void pull2(const float* __restrict__ s_pp, const float* __restrict__ s_ap,
           const int* __restrict__ csr_pp, const int* __restrict__ rs_pp,
           const int* __restrict__ cnt_pp,
           const int* __restrict__ csr_ap, const int* __restrict__ rs_ap,
           const int* __restrict__ cnt_ap,
           float* __restrict__ out, int N)
{
    int g = (blockIdx.x * blockDim.x + threadIdx.x) >> 2;
    int c = threadIdx.x & 3;
    if (g >= N) return;
    int s1 = rs_pp[g], k1 = cnt_pp[g], e1 = s1 + k1;
    float t = 0.f;
    for (int j = s1 + c; j < e1; j += 4) t += s_pp[ntl(csr_pp + j)];
    int s2 = rs_ap[g], k2 = cnt_ap[g], e2 = s2 + k2;
    float u = 0.f;
    for (int j = s2 + c; j < e2; j += 4) u += s_ap[ntl(csr_ap + j)];
    t += __shfl_xor(t, 1); t += __shfl_xor(t, 2);
    u += __shfl_xor(u, 1); u += __shfl_xor(u, 2);
    if (c == 0) {
        out[g] += t / fmaxf((float)k1, 1.f) + u / fmaxf((float)k2, 1.f);
    }
}

extern "C" void kernel_launch(void* const* d_in, const int* in_sizes, int n_in,
                              void* d_out, int out_size, void* d_ws, size_t ws_size,
                              hipStream_t stream)
{
    const float* x_paper  = (const float*)d_in[0];
    const float* x_author = (const float*)d_in[1];
    const int* src_pp = (const int*)d_in[2];
    const int* dst_pp = (const int*)d_in[3];
    const int* src_ap = (const int*)d_in[4];
    const int* dst_ap = (const int*)d_in[5];
    const int* src_pa = (const int*)d_in[6];
    const int* dst_pa = (const int*)d_in[7];
    const float* Wl1_pp = (const float*)d_in[8];
    const float* bl1_pp = (const float*)d_in[9];
    const float* Wr1_pp = (const float*)d_in[10];
    const float* Wl1_ap = (const float*)d_in[11];
    const float* bl1_ap = (const float*)d_in[12];
    const float* Wr1_ap = (const float*)d_in[13];
    const float* Wl1_pa = (const float*)d_in[14];
    const float* bl1_pa = (const float*)d_in[15];
    const float* Wr1_pa = (const float*)d_in[16];
    const float* Wl2_pp = (const float*)d_in[17];
    const float* bl2_pp = (const float*)d_in[18];
    const float* Wr2_pp = (const float*)d_in[19];
    const float* Wl2_ap = (const float*)d_in[20];
    const float* bl2_ap = (const float*)d_in[21];
    const float* Wr2_ap = (const float*)d_in[22];
    const float* W_lin  = (const float*)d_in[23];
    const float* b_lin  = (const float*)d_in[24];

    const int NP = in_sizes[0] / 64;
    const int NA = in_sizes[1] / 64;
    const int E_PP = in_sizes[2];
    const int E_AP = in_sizes[4];
    const int E_PA = in_sizes[6];
    const int S = 2 * NP + NA;    // counters per histogram copy

    // ---- workspace ----
    char* wp = (char*)d_ws;
    int* cnt8  = (int*)wp;          wp += (size_t)8 * S * 4;   // zeroed
    int* queue = (int*)wp;          wp += 32 * 4;              // zeroed (totals at [24..26])
    int* cnt   = (int*)wp;          wp += (size_t)S * 4;
    int* rs    = (int*)wp;          wp += (size_t)S * 4;
    int* rn    = (int*)wp;          wp += (size_t)S * 4;
    int* csr_pp = (int*)wp;         wp += (size_t)E_PP * 4;
    int* csr_ap = (int*)wp;         wp += (size_t)E_AP * 4;
    int* csr_pa = (int*)wp;         wp += (size_t)E_PA * 4;
    ushort_t* h_pp = (ushort_t*)wp; wp += (size_t)NP * 32 * 2;
    ushort_t* h_pa = (ushort_t*)wp; wp += (size_t)NP * 32 * 2;
    ushort_t* h_ap = (ushort_t*)wp; wp += (size_t)NA * 32 * 2;
    float* root_p = (float*)wp;     wp += (size_t)NP * 32 * 4;
    float* root_a = (float*)wp;     wp += (size_t)NA * 32 * 4;
    float* s_pp   = (float*)wp;     wp += (size_t)NP * 4;
    float* s_ap   = (float*)wp;     wp += (size_t)NA * 4;
    float* Wcomb_p = (float*)wp;    wp += 64 * 96 * 4;
    float* Wcomb_a = (float*)wp;    wp += 64 * 64 * 4;
    float* bias_p = (float*)wp;     wp += 32 * 4;
    float* bias_a = (float*)wp;     wp += 32 * 4;
    float* vv     = (float*)wp;     wp += 128 * 4;

    int* cnt_pp = cnt,  * cnt_ap = cnt + NP,  * cnt_pa = cnt + 2 * NP;
    int* rs_pp  = rs,   * rs_ap  = rs + NP,   * rs_pa  = rs + 2 * NP;
    int* rn_pp  = rn,   * rn_ap  = rn + NP,   * rn_pa  = rn + 2 * NP;

    float* out = (float*)d_out;

    const int np_pass = (NP + (1 << WBITS) - 1) >> WBITS;   // 7
    const int na_pass = (NA + (1 << WBITS) - 1) >> WBITS;   // 4

    // zero the 8 private histograms + queue/totals (contiguous at ws start)
    hipMemsetAsync(d_ws, 0, ((size_t)8 * S + 32) * sizeof(int), stream);

    prep_weights<<<1, 256, 0, stream>>>(
        Wl1_pp, Wr1_pp, Wl1_ap, Wr1_ap, Wl1_pa, Wr1_pa,
        bl1_pp, bl1_ap, bl1_pa,
        Wl2_pp, bl2_pp, Wr2_pp, Wl2_ap, bl2_ap, Wr2_ap,
        W_lin, b_lin, Wcomb_p, Wcomb_a, bias_p, bias_a, vv);

    count8<<<2048, 256, 0, stream>>>(dst_pp, E_PP, dst_ap, E_AP, dst_pa, E_PA,
                                     cnt8, S, NP);

    scan8<<<(NP + 2047) / 2048, 256, 0, stream>>>(cnt8 + 0,      S, cnt_pp, rs_pp, rn_pp, queue + 24, NP);
    scan8<<<(NP + 2047) / 2048, 256, 0, stream>>>(cnt8 + NP,     S, cnt_ap, rs_ap, rn_ap, queue + 25, NP);
    scan8<<<(NA + 2047) / 2048, 256, 0, stream>>>(cnt8 + 2 * NP, S, cnt_pa, rs_pa, rn_pa, queue + 26, NA);

    fill_q<<<2048, 256, 0, stream>>>(
        src_pp, dst_pp, rn_pp, csr_pp, E_PP, np_pass,
        src_ap, dst_ap, rn_ap, csr_ap, E_AP, np_pass,
        src_pa, dst_pa, rn_pa, csr_pa, E_PA, na_pass,
        queue);

    proj_paper<<<(NP + 7) / 8, 256, 0, stream>>>(x_paper, Wcomb_p, bias_p, h_pp, h_pa, root_p, NP);
    proj_author<<<(NA + 7) / 8, 256, 0, stream>>>(x_author, Wcomb_a, bias_a, h_ap, root_a, NA);

    pull_paper<<<(NP + 15) / 16, 256, 0, stream>>>(
        h_pp, h_ap, root_p, csr_pp, rs_pp, cnt_pp, csr_ap, rs_ap, cnt_ap,
        vv, s_pp, out, NP);
    pull_author<<<(NA + 15) / 16, 256, 0, stream>>>(
        h_pa, root_a, csr_pa, rs_pa, cnt_pa, vv, s_ap, NA);

    pull2<<<((size_t)NP * 4 + 255) / 256, 256, 0, stream>>>(
        s_pp, s_ap, csr_pp, rs_pp, cnt_pp, csr_ap, rs_ap, cnt_ap, out, NP);
}

// Round 10
// 811.018 us; speedup vs baseline: 1.2643x; 1.2643x over previous
//
#include <hip/hip_runtime.h>

// ---------------------------------------------------------------------------
// HeteroSAGE: CSR pull; CSR built with ZERO per-edge global atomics:
//   partition_k: chunk edges -> per-window LDS counts -> claim bucket runs ->
//                coalesced packed writes ((dlow<<18)|src, 4B/edge)
//   fill_win:    one block per 8192-dst window: LDS hist -> LDS scan ->
//                cnt/rs coalesced + csr placement via LDS atomics; window's
//                bucket+csr are co-resident in one XCD L2 (full-line writes).
//   proj (h bf16 + root f32, root_p overlays dead buckets) ->
//   pull (8 waves/EU, unroll-4 gathers) -> pull2 scalar layer-2.
// ---------------------------------------------------------------------------

typedef unsigned short ushort_t;

#define PWBITS 13
#define PWIN   (1 << PWBITS)     // 8192 dsts per window
#define PCHUNK 8192              // edges per partition block
#define CAPPAD 16384             // bucket slack (~45 sigma)

__device__ inline ushort_t f2bf(float f) {
    unsigned u = __float_as_uint(f);
    unsigned r = (u + 0x7FFFu + ((u >> 16) & 1u)) >> 16;
    return (ushort_t)r;
}
__device__ inline float bf2f_lo(unsigned u) { return __uint_as_float(u << 16); }
__device__ inline float bf2f_hi(unsigned u) { return __uint_as_float(u & 0xFFFF0000u); }
__device__ inline int ntl(const int* p) { return __builtin_nontemporal_load(p); }

__global__ void prep_weights(
    const float* __restrict__ Wl1_pp, const float* __restrict__ Wr1_pp,
    const float* __restrict__ Wl1_ap, const float* __restrict__ Wr1_ap,
    const float* __restrict__ Wl1_pa, const float* __restrict__ Wr1_pa,
    const float* __restrict__ bl1_pp, const float* __restrict__ bl1_ap,
    const float* __restrict__ bl1_pa,
    const float* __restrict__ Wl2_pp, const float* __restrict__ bl2_pp,
    const float* __restrict__ Wr2_pp,
    const float* __restrict__ Wl2_ap, const float* __restrict__ bl2_ap,
    const float* __restrict__ Wr2_ap,
    const float* __restrict__ W_lin, const float* __restrict__ b_lin,
    float* __restrict__ Wcomb_p,  // 64 x 96: [Wl1_pp | Wl1_pa | Wr1_pp+Wr1_ap]
    float* __restrict__ Wcomb_a,  // 64 x 64: [Wl1_ap | Wr1_pa]
    float* __restrict__ bias_p,   // 32
    float* __restrict__ bias_a,   // 32
    float* __restrict__ vv)       // [0:32) v_pp  [32:64) v_r  [64] c2  [96:128) v_ap
{
    int t = threadIdx.x;
    for (int idx = t; idx < 64 * 96; idx += 256) {
        int i = idx / 96, j = idx % 96;
        float v;
        if (j < 32)       v = Wl1_pp[i * 32 + j];
        else if (j < 64)  v = Wl1_pa[i * 32 + (j - 32)];
        else              v = Wr1_pp[i * 32 + (j - 64)] + Wr1_ap[i * 32 + (j - 64)];
        Wcomb_p[idx] = v;
    }
    for (int idx = t; idx < 64 * 64; idx += 256) {
        int i = idx / 64, j = idx % 64;
        Wcomb_a[idx] = (j < 32) ? Wl1_ap[i * 32 + j] : Wr1_pa[i * 32 + (j - 32)];
    }
    if (t < 32) {
        bias_p[t] = bl1_pp[t] + bl1_ap[t];
        bias_a[t] = bl1_pa[t];
        float vpp = 0.f, vr = 0.f, vap = 0.f;
        for (int j = 0; j < 32; ++j) {
            float wl = W_lin[j];
            vpp += Wl2_pp[t * 32 + j] * wl;
            vr  += (Wr2_pp[t * 32 + j] + Wr2_ap[t * 32 + j]) * wl;
            vap += Wl2_ap[t * 32 + j] * wl;
        }
        vv[t] = vpp; vv[32 + t] = vr; vv[96 + t] = vap;
    }
    if (t == 0) {
        float c = b_lin[0];
        for (int j = 0; j < 32; ++j) c += (bl2_pp[j] + bl2_ap[j]) * W_lin[j];
        vv[64] = c;
    }
}

// group edges by dst-window: LDS counts -> claim contiguous bucket runs ->
// coalesced packed writes. Packed word: (d_low13 << 18) | src  (src < 2^18).
__global__ void partition_k(const int* __restrict__ src, const int* __restrict__ dst,
                            int E, unsigned* __restrict__ bucket, int cap,
                            int* __restrict__ wcur)
{
    __shared__ int lcnt[32];
    __shared__ int lbase[32];
    int e0 = blockIdx.x * PCHUNK;
    int e1 = e0 + PCHUNK; if (e1 > E) e1 = E;
    if (threadIdx.x < 32) lcnt[threadIdx.x] = 0;
    __syncthreads();
    for (int e = e0 + threadIdx.x; e < e1; e += blockDim.x)
        atomicAdd(&lcnt[((unsigned)ntl(dst + e)) >> PWBITS], 1);
    __syncthreads();
    if (threadIdx.x < 32) {
        int c = lcnt[threadIdx.x];
        lbase[threadIdx.x] = (c > 0) ? atomicAdd(&wcur[threadIdx.x], c) : 0;
        lcnt[threadIdx.x] = 0;
    }
    __syncthreads();
    for (int e = e0 + threadIdx.x; e < e1; e += blockDim.x) {
        int d = ntl(dst + e);
        int w = ((unsigned)d) >> PWBITS;
        int off = lbase[w] + atomicAdd(&lcnt[w], 1);
        if (off < cap)
            bucket[(size_t)w * cap + off] =
                (((unsigned)(d & (PWIN - 1))) << 18) | (unsigned)ntl(src + e);
    }
}

// one block per window: LDS hist -> cnt out -> LDS exclusive scan -> rs out ->
// csr placement via LDS atomics. csr region for window w = [w*cap, ...).
__global__ __launch_bounds__(1024)
void fill_win(const unsigned* __restrict__ bucket, const int* __restrict__ wcur,
              int cap, int* __restrict__ csr, int* __restrict__ cnt,
              int* __restrict__ rs, int N)
{
    __shared__ int lc[PWIN];
    __shared__ int wsum[16], wpre[16];
    int w = blockIdx.x;
    int d0 = w << PWBITS;
    int sz = wcur[w]; if (sz > cap) sz = cap;
    const unsigned* b = bucket + (size_t)w * cap;
    for (int i = threadIdx.x; i < PWIN; i += 1024) lc[i] = 0;
    __syncthreads();
    for (int i = threadIdx.x; i < sz; i += 1024)
        atomicAdd(&lc[b[i] >> 18], 1);
    __syncthreads();
    for (int i = threadIdx.x; i < PWIN; i += 1024) {
        int d = d0 + i;
        if (d < N) cnt[d] = lc[i];
    }
    __syncthreads();
    // exclusive scan of lc (8 elements/thread), base = w*cap
    int bi = threadIdx.x * 8;
    int v[8]; int ts = 0;
#pragma unroll
    for (int k = 0; k < 8; ++k) { v[k] = lc[bi + k]; ts += v[k]; }
    int lane = threadIdx.x & 63;
    int incl = ts;
#pragma unroll
    for (int off = 1; off < 64; off <<= 1) {
        int o = __shfl_up(incl, off);
        if (lane >= off) incl += o;
    }
    int wid = threadIdx.x >> 6;
    if (lane == 63) wsum[wid] = incl;
    __syncthreads();
    if (threadIdx.x == 0) {
        int r = 0;
        for (int i = 0; i < 16; ++i) { wpre[i] = r; r += wsum[i]; }
    }
    __syncthreads();
    int run = w * cap + wpre[wid] + (incl - ts);
#pragma unroll
    for (int k = 0; k < 8; ++k) {
        int d = d0 + bi + k;
        lc[bi + k] = run;
        if (d < N) rs[d] = run;
        run += v[k];
    }
    __syncthreads();
    for (int i = threadIdx.x; i < sz; i += 1024) {
        unsigned u = b[i];
        int pos = atomicAdd(&lc[u >> 18], 1);
        csr[pos] = (int)(u & 0x3FFFFu);
    }
}

// paper projection: h_pp, h_pa (bf16 neighbor features) + root_p (f32, incl bias)
__global__ void proj_paper(const float* __restrict__ x, const float* __restrict__ Wc,
                           const float* __restrict__ bias,
                           ushort_t* __restrict__ h_pp, ushort_t* __restrict__ h_pa,
                           float* __restrict__ root_p, int N)
{
    __shared__ float Wlds[64 * 96];
    __shared__ float blds[32];
    for (int i = threadIdx.x; i < 64 * 96; i += 256) Wlds[i] = Wc[i];
    if (threadIdx.x < 32) blds[threadIdx.x] = bias[threadIdx.x];
    __syncthreads();
    int n = blockIdx.x * 8 + (threadIdx.x >> 5);
    int c = threadIdx.x & 31;
    if (n < N) {
        const float* xr = x + (size_t)n * 64;
        float a0 = 0.f, a1 = 0.f, a2 = 0.f;
#pragma unroll
        for (int i = 0; i < 64; ++i) {
            float xv = xr[i];
            a0 += xv * Wlds[i * 96 + c];
            a1 += xv * Wlds[i * 96 + 32 + c];
            a2 += xv * Wlds[i * 96 + 64 + c];
        }
        h_pp[(size_t)n * 32 + c] = f2bf(a0);
        h_pa[(size_t)n * 32 + c] = f2bf(a1);
        root_p[(size_t)n * 32 + c] = a2 + blds[c];
    }
}

__global__ void proj_author(const float* __restrict__ x, const float* __restrict__ Wc,
                            const float* __restrict__ bias,
                            ushort_t* __restrict__ h_ap, float* __restrict__ root_a, int N)
{
    __shared__ float Wlds[64 * 64];
    __shared__ float blds[32];
    for (int i = threadIdx.x; i < 64 * 64; i += 256) Wlds[i] = Wc[i];
    if (threadIdx.x < 32) blds[threadIdx.x] = bias[threadIdx.x];
    __syncthreads();
    int n = blockIdx.x * 8 + (threadIdx.x >> 5);
    int c = threadIdx.x & 31;
    if (n < N) {
        const float* xr = x + (size_t)n * 64;
        float a0 = 0.f, a1 = 0.f;
#pragma unroll
        for (int i = 0; i < 64; ++i) {
            float xv = xr[i];
            a0 += xv * Wlds[i * 64 + c];
            a1 += xv * Wlds[i * 64 + 32 + c];
        }
        h_ap[(size_t)n * 32 + c] = f2bf(a0);
        root_a[(size_t)n * 32 + c] = a1 + blds[c];
    }
}

// 16 lanes/node, 2 cols/lane, tiny LDS, high occupancy. Unroll-4 independent
// gathers; fuses mean + root + relu + layer-2 dot products.
__global__ __launch_bounds__(256, 8)
void pull_paper(const ushort_t* __restrict__ h_pp, const ushort_t* __restrict__ h_ap,
                const float* __restrict__ root,
                const int* __restrict__ csr_pp, const int* __restrict__ rs_pp,
                const int* __restrict__ cnt_pp,
                const int* __restrict__ csr_ap, const int* __restrict__ rs_ap,
                const int* __restrict__ cnt_ap,
                const float* __restrict__ vv,
                float* __restrict__ s_pp, float* __restrict__ out, int N)
{
    __shared__ float v0[32], v1[32];
    __shared__ float c2s;
    if (threadIdx.x < 32) { v0[threadIdx.x] = vv[threadIdx.x]; v1[threadIdx.x] = vv[32 + threadIdx.x]; }
    if (threadIdx.x == 0) c2s = vv[64];
    __syncthreads();
    int n = blockIdx.x * 16 + (threadIdx.x >> 4);
    if (n >= N) return;
    int c = threadIdx.x & 15;
    const ushort_t* hpp_c = h_pp + 2 * c;
    const ushort_t* hap_c = h_ap + 2 * c;
    int s1 = rs_pp[n], k1 = cnt_pp[n], e1 = s1 + k1;
    float a0 = 0.f, a1 = 0.f;
    int j = s1;
    for (; j + 4 <= e1; j += 4) {
        int i0 = ntl(csr_pp + j), i1 = ntl(csr_pp + j + 1);
        int i2 = ntl(csr_pp + j + 2), i3 = ntl(csr_pp + j + 3);
        unsigned u0 = *(const unsigned*)(hpp_c + (size_t)i0 * 32);
        unsigned u1 = *(const unsigned*)(hpp_c + (size_t)i1 * 32);
        unsigned u2 = *(const unsigned*)(hpp_c + (size_t)i2 * 32);
        unsigned u3 = *(const unsigned*)(hpp_c + (size_t)i3 * 32);
        a0 += (bf2f_lo(u0) + bf2f_lo(u1)) + (bf2f_lo(u2) + bf2f_lo(u3));
        a1 += (bf2f_hi(u0) + bf2f_hi(u1)) + (bf2f_hi(u2) + bf2f_hi(u3));
    }
    for (; j < e1; ++j) {
        unsigned u0 = *(const unsigned*)(hpp_c + (size_t)ntl(csr_pp + j) * 32);
        a0 += bf2f_lo(u0); a1 += bf2f_hi(u0);
    }
    int s2 = rs_ap[n], k2 = cnt_ap[n], e2 = s2 + k2;
    float b0 = 0.f, b1 = 0.f;
    j = s2;
    for (; j + 4 <= e2; j += 4) {
        int i0 = ntl(csr_ap + j), i1 = ntl(csr_ap + j + 1);
        int i2 = ntl(csr_ap + j + 2), i3 = ntl(csr_ap + j + 3);
        unsigned u0 = *(const unsigned*)(hap_c + (size_t)i0 * 32);
        unsigned u1 = *(const unsigned*)(hap_c + (size_t)i1 * 32);
        unsigned u2 = *(const unsigned*)(hap_c + (size_t)i2 * 32);
        unsigned u3 = *(const unsigned*)(hap_c + (size_t)i3 * 32);
        b0 += (bf2f_lo(u0) + bf2f_lo(u1)) + (bf2f_lo(u2) + bf2f_lo(u3));
        b1 += (bf2f_hi(u0) + bf2f_hi(u1)) + (bf2f_hi(u2) + bf2f_hi(u3));
    }
    for (; j < e2; ++j) {
        unsigned u0 = *(const unsigned*)(hap_c + (size_t)ntl(csr_ap + j) * 32);
        b0 += bf2f_lo(u0); b1 += bf2f_hi(u0);
    }
    float ipp = 1.0f / fmaxf((float)k1, 1.0f);
    float iap = 1.0f / fmaxf((float)k2, 1.0f);
    float p0 = fmaxf(root[(size_t)n * 32 + 2 * c]     + a0 * ipp + b0 * iap, 0.f);
    float p1 = fmaxf(root[(size_t)n * 32 + 2 * c + 1] + a1 * ipp + b1 * iap, 0.f);
    float d0 = p0 * v0[2 * c] + p1 * v0[2 * c + 1];
    float d1 = p0 * v1[2 * c] + p1 * v1[2 * c + 1];
#pragma unroll
    for (int off = 1; off < 16; off <<= 1) {
        d0 += __shfl_xor(d0, off);
        d1 += __shfl_xor(d1, off);
    }
    if (c == 0) { s_pp[n] = d0; out[n] = d1 + c2s; }
}

__global__ __launch_bounds__(256, 8)
void pull_author(const ushort_t* __restrict__ h_pa, const float* __restrict__ root,
                 const int* __restrict__ csr_pa, const int* __restrict__ rs_pa,
                 const int* __restrict__ cnt_pa,
                 const float* __restrict__ vv, float* __restrict__ s_ap, int N)
{
    __shared__ float v0[32];
    if (threadIdx.x < 32) v0[threadIdx.x] = vv[96 + threadIdx.x];
    __syncthreads();
    int n = blockIdx.x * 16 + (threadIdx.x >> 4);
    if (n >= N) return;
    int c = threadIdx.x & 15;
    const ushort_t* hpa_c = h_pa + 2 * c;
    int s1 = rs_pa[n], k1 = cnt_pa[n], e1 = s1 + k1;
    float a0 = 0.f, a1 = 0.f;
    int j = s1;
    for (; j + 4 <= e1; j += 4) {
        int i0 = ntl(csr_pa + j), i1 = ntl(csr_pa + j + 1);
        int i2 = ntl(csr_pa + j + 2), i3 = ntl(csr_pa + j + 3);
        unsigned u0 = *(const unsigned*)(hpa_c + (size_t)i0 * 32);
        unsigned u1 = *(const unsigned*)(hpa_c + (size_t)i1 * 32);
        unsigned u2 = *(const unsigned*)(hpa_c + (size_t)i2 * 32);
        unsigned u3 = *(const unsigned*)(hpa_c + (size_t)i3 * 32);
        a0 += (bf2f_lo(u0) + bf2f_lo(u1)) + (bf2f_lo(u2) + bf2f_lo(u3));
        a1 += (bf2f_hi(u0) + bf2f_hi(u1)) + (bf2f_hi(u2) + bf2f_hi(u3));
    }
    for (; j < e1; ++j) {
        unsigned u0 = *(const unsigned*)(hpa_c + (size_t)ntl(csr_pa + j) * 32);
        a0 += bf2f_lo(u0); a1 += bf2f_hi(u0);
    }
    float ip = 1.0f / fmaxf((float)k1, 1.0f);
    float p0 = fmaxf(root[(size_t)n * 32 + 2 * c]     + a0 * ip, 0.f);
    float p1 = fmaxf(root[(size_t)n * 32 + 2 * c + 1] + a1 * ip, 0.f);
    float d0 = p0 * v0[2 * c] + p1 * v0[2 * c + 1];
#pragma unroll
    for (int off = 1; off < 16; off <<= 1) d0 += __shfl_xor(d0, off);
    if (c == 0) s_ap[n] = d0;
}

// layer-2 scalar pull, 4 lanes/node.
__global__ __launch_bounds__(256, 8)
void pull2(const float* __restrict__ s_pp, const float* __restrict__ s_ap,
           const int* __restrict__ csr_pp, const int* __restrict__ rs_pp,
           const int* __restrict__ cnt_pp,
           const int* __restrict__ csr_ap, const int* __restrict__ rs_ap,
           const int* __restrict__ cnt_ap,
           float* __restrict__ out, int N)
{
    int g = (blockIdx.x * blockDim.x + threadIdx.x) >> 2;
    int c = threadIdx.x & 3;
    if (g >= N) return;
    int s1 = rs_pp[g], k1 = cnt_pp[g], e1 = s1 + k1;
    float t = 0.f;
    for (int j = s1 + c; j < e1; j += 4) t += s_pp[ntl(csr_pp + j)];
    int s2 = rs_ap[g], k2 = cnt_ap[g], e2 = s2 + k2;
    float u = 0.f;
    for (int j = s2 + c; j < e2; j += 4) u += s_ap[ntl(csr_ap + j)];
    t += __shfl_xor(t, 1); t += __shfl_xor(t, 2);
    u += __shfl_xor(u, 1); u += __shfl_xor(u, 2);
    if (c == 0) {
        out[g] += t / fmaxf((float)k1, 1.f) + u / fmaxf((float)k2, 1.f);
    }
}

extern "C" void kernel_launch(void* const* d_in, const int* in_sizes, int n_in,
                              void* d_out, int out_size, void* d_ws, size_t ws_size,
                              hipStream_t stream)
{
    const float* x_paper  = (const float*)d_in[0];
    const float* x_author = (const float*)d_in[1];
    const int* src_pp = (const int*)d_in[2];
    const int* dst_pp = (const int*)d_in[3];
    const int* src_ap = (const int*)d_in[4];
    const int* dst_ap = (const int*)d_in[5];
    const int* src_pa = (const int*)d_in[6];
    const int* dst_pa = (const int*)d_in[7];
    const float* Wl1_pp = (const float*)d_in[8];
    const float* bl1_pp = (const float*)d_in[9];
    const float* Wr1_pp = (const float*)d_in[10];
    const float* Wl1_ap = (const float*)d_in[11];
    const float* bl1_ap = (const float*)d_in[12];
    const float* Wr1_ap = (const float*)d_in[13];
    const float* Wl1_pa = (const float*)d_in[14];
    const float* bl1_pa = (const float*)d_in[15];
    const float* Wr1_pa = (const float*)d_in[16];
    const float* Wl2_pp = (const float*)d_in[17];
    const float* bl2_pp = (const float*)d_in[18];
    const float* Wr2_pp = (const float*)d_in[19];
    const float* Wl2_ap = (const float*)d_in[20];
    const float* bl2_ap = (const float*)d_in[21];
    const float* Wr2_ap = (const float*)d_in[22];
    const float* W_lin  = (const float*)d_in[23];
    const float* b_lin  = (const float*)d_in[24];

    const int NP = in_sizes[0] / 64;
    const int NA = in_sizes[1] / 64;
    const int E_PP = in_sizes[2];
    const int E_AP = in_sizes[4];
    const int E_PA = in_sizes[6];

    const int nw_pp = (NP + PWIN - 1) >> PWBITS;   // 25
    const int nw_ap = nw_pp;                       // 25
    const int nw_pa = (NA + PWIN - 1) >> PWBITS;   // 13
    const int cap_pp = E_PP / nw_pp + CAPPAD;
    const int cap_ap = E_AP / nw_ap + CAPPAD;
    const int cap_pa = E_PA / nw_pa + CAPPAD;

    // ---- workspace ----
    char* wp = (char*)d_ws;
    int* wcur = (int*)wp;             wp += 96 * 4;   // 3 x 32, zeroed
    unsigned* bk_pp = (unsigned*)wp;  wp += (size_t)nw_pp * cap_pp * 4;
    unsigned* bk_ap = (unsigned*)wp;  wp += (size_t)nw_ap * cap_ap * 4;
    unsigned* bk_pa = (unsigned*)wp;  wp += (size_t)nw_pa * cap_pa * 4;
    int* csr_pp = (int*)wp;           wp += (size_t)nw_pp * cap_pp * 4;
    int* csr_ap = (int*)wp;           wp += (size_t)nw_ap * cap_ap * 4;
    int* csr_pa = (int*)wp;           wp += (size_t)nw_pa * cap_pa * 4;
    int* cnt    = (int*)wp;           wp += (size_t)(2 * NP + NA) * 4;
    int* rs     = (int*)wp;           wp += (size_t)(2 * NP + NA) * 4;
    ushort_t* h_pp = (ushort_t*)wp;   wp += (size_t)NP * 32 * 2;
    ushort_t* h_pa = (ushort_t*)wp;   wp += (size_t)NP * 32 * 2;
    ushort_t* h_ap = (ushort_t*)wp;   wp += (size_t)NA * 32 * 2;
    float* root_a = (float*)wp;       wp += (size_t)NA * 32 * 4;
    float* s_pp   = (float*)wp;       wp += (size_t)NP * 4;
    float* s_ap   = (float*)wp;       wp += (size_t)NA * 4;
    float* Wcomb_p = (float*)wp;      wp += 64 * 96 * 4;
    float* Wcomb_a = (float*)wp;      wp += 64 * 64 * 4;
    float* bias_p = (float*)wp;       wp += 32 * 4;
    float* bias_a = (float*)wp;       wp += 32 * 4;
    float* vv     = (float*)wp;       wp += 128 * 4;
    // root_p overlays the (dead after fill_win) bucket region
    float* root_p = (float*)bk_pp;    // needs NP*32*4 = 25.6MB <= buckets ~29MB

    int* cnt_pp = cnt,  * cnt_ap = cnt + NP,  * cnt_pa = cnt + 2 * NP;
    int* rs_pp  = rs,   * rs_ap  = rs + NP,   * rs_pa  = rs + 2 * NP;

    float* out = (float*)d_out;

    // zero the window cursors only
    hipMemsetAsync(wcur, 0, 96 * sizeof(int), stream);

    prep_weights<<<1, 256, 0, stream>>>(
        Wl1_pp, Wr1_pp, Wl1_ap, Wr1_ap, Wl1_pa, Wr1_pa,
        bl1_pp, bl1_ap, bl1_pa,
        Wl2_pp, bl2_pp, Wr2_pp, Wl2_ap, bl2_ap, Wr2_ap,
        W_lin, b_lin, Wcomb_p, Wcomb_a, bias_p, bias_a, vv);

    partition_k<<<(E_PP + PCHUNK - 1) / PCHUNK, 256, 0, stream>>>(
        src_pp, dst_pp, E_PP, bk_pp, cap_pp, wcur + 0);
    partition_k<<<(E_AP + PCHUNK - 1) / PCHUNK, 256, 0, stream>>>(
        src_ap, dst_ap, E_AP, bk_ap, cap_ap, wcur + 32);
    partition_k<<<(E_PA + PCHUNK - 1) / PCHUNK, 256, 0, stream>>>(
        src_pa, dst_pa, E_PA, bk_pa, cap_pa, wcur + 64);

    fill_win<<<nw_pp, 1024, 0, stream>>>(bk_pp, wcur + 0,  cap_pp, csr_pp, cnt_pp, rs_pp, NP);
    fill_win<<<nw_ap, 1024, 0, stream>>>(bk_ap, wcur + 32, cap_ap, csr_ap, cnt_ap, rs_ap, NP);
    fill_win<<<nw_pa, 1024, 0, stream>>>(bk_pa, wcur + 64, cap_pa, csr_pa, cnt_pa, rs_pa, NA);

    proj_paper<<<(NP + 7) / 8, 256, 0, stream>>>(x_paper, Wcomb_p, bias_p, h_pp, h_pa, root_p, NP);
    proj_author<<<(NA + 7) / 8, 256, 0, stream>>>(x_author, Wcomb_a, bias_a, h_ap, root_a, NA);

    pull_paper<<<(NP + 15) / 16, 256, 0, stream>>>(
        h_pp, h_ap, root_p, csr_pp, rs_pp, cnt_pp, csr_ap, rs_ap, cnt_ap,
        vv, s_pp, out, NP);
    pull_author<<<(NA + 15) / 16, 256, 0, stream>>>(
        h_pa, root_a, csr_pa, rs_pa, cnt_pa, vv, s_ap, NA);

    pull2<<<((size_t)NP * 4 + 255) / 256, 256, 0, stream>>>(
        s_pp, s_ap, csr_pp, rs_pp, cnt_pp, csr_ap, rs_ap, cnt_ap, out, NP);
}

// Round 11
// 542.094 us; speedup vs baseline: 1.8915x; 1.4961x over previous
//
#include <hip/hip_runtime.h>

// ---------------------------------------------------------------------------
// HeteroSAGE: CSR pull; CSR built with ZERO per-edge global atomics.
//   partition3: (one launch) chunk edges -> per-window LDS counts -> claim
//               bucket runs -> coalesced packed writes ((dlow10<<18)|src).
//   fill_win3:  (one launch) one 256-thr block per 1024-dst window:
//               LDS hist -> LDS scan -> cnt/rs coalesced + csr via LDS
//               atomics; bucket+csr slice are L2-resident (full-line writes).
//   proj (h bf16 + root f32, root_p overlays dead buckets) ->
//   pull (8 waves/EU, unroll-4 gathers) -> pull2 scalar layer-2.
// ---------------------------------------------------------------------------

typedef unsigned short ushort_t;

#define PWBITS 10
#define PWIN   (1 << PWBITS)     // 1024 dsts per window
#define PCHUNK 8192              // edges per partition chunk
#define CAPPAD 4096              // bucket slack (~32 sigma)

__device__ inline ushort_t f2bf(float f) {
    unsigned u = __float_as_uint(f);
    unsigned r = (u + 0x7FFFu + ((u >> 16) & 1u)) >> 16;
    return (ushort_t)r;
}
__device__ inline float bf2f_lo(unsigned u) { return __uint_as_float(u << 16); }
__device__ inline float bf2f_hi(unsigned u) { return __uint_as_float(u & 0xFFFF0000u); }
__device__ inline int ntl(const int* p) { return __builtin_nontemporal_load(p); }
__device__ inline unsigned ntlu(const unsigned* p) { return __builtin_nontemporal_load(p); }

__global__ void prep_weights(
    const float* __restrict__ Wl1_pp, const float* __restrict__ Wr1_pp,
    const float* __restrict__ Wl1_ap, const float* __restrict__ Wr1_ap,
    const float* __restrict__ Wl1_pa, const float* __restrict__ Wr1_pa,
    const float* __restrict__ bl1_pp, const float* __restrict__ bl1_ap,
    const float* __restrict__ bl1_pa,
    const float* __restrict__ Wl2_pp, const float* __restrict__ bl2_pp,
    const float* __restrict__ Wr2_pp,
    const float* __restrict__ Wl2_ap, const float* __restrict__ bl2_ap,
    const float* __restrict__ Wr2_ap,
    const float* __restrict__ W_lin, const float* __restrict__ b_lin,
    float* __restrict__ Wcomb_p,  // 64 x 96: [Wl1_pp | Wl1_pa | Wr1_pp+Wr1_ap]
    float* __restrict__ Wcomb_a,  // 64 x 64: [Wl1_ap | Wr1_pa]
    float* __restrict__ bias_p,   // 32
    float* __restrict__ bias_a,   // 32
    float* __restrict__ vv)       // [0:32) v_pp  [32:64) v_r  [64] c2  [96:128) v_ap
{
    int t = threadIdx.x;
    for (int idx = t; idx < 64 * 96; idx += 256) {
        int i = idx / 96, j = idx % 96;
        float v;
        if (j < 32)       v = Wl1_pp[i * 32 + j];
        else if (j < 64)  v = Wl1_pa[i * 32 + (j - 32)];
        else              v = Wr1_pp[i * 32 + (j - 64)] + Wr1_ap[i * 32 + (j - 64)];
        Wcomb_p[idx] = v;
    }
    for (int idx = t; idx < 64 * 64; idx += 256) {
        int i = idx / 64, j = idx % 64;
        Wcomb_a[idx] = (j < 32) ? Wl1_ap[i * 32 + j] : Wr1_pa[i * 32 + (j - 32)];
    }
    if (t < 32) {
        bias_p[t] = bl1_pp[t] + bl1_ap[t];
        bias_a[t] = bl1_pa[t];
        float vpp = 0.f, vr = 0.f, vap = 0.f;
        for (int j = 0; j < 32; ++j) {
            float wl = W_lin[j];
            vpp += Wl2_pp[t * 32 + j] * wl;
            vr  += (Wr2_pp[t * 32 + j] + Wr2_ap[t * 32 + j]) * wl;
            vap += Wl2_ap[t * 32 + j] * wl;
        }
        vv[t] = vpp; vv[32 + t] = vr; vv[96 + t] = vap;
    }
    if (t == 0) {
        float c = b_lin[0];
        for (int j = 0; j < 32; ++j) c += (bl2_pp[j] + bl2_ap[j]) * W_lin[j];
        vv[64] = c;
    }
}

// one launch, all 3 relations: group edges by dst-window via LDS counts +
// claimed contiguous bucket runs; packed coalesced writes.
__global__ __launch_bounds__(256)
void partition3(
    const int* __restrict__ src0, const int* __restrict__ dst0, int E0,
    unsigned* __restrict__ bk0, int cap0, int nw0, int* __restrict__ wc0,
    const int* __restrict__ src1, const int* __restrict__ dst1, int E1,
    unsigned* __restrict__ bk1, int cap1, int nw1, int* __restrict__ wc1,
    const int* __restrict__ src2, const int* __restrict__ dst2, int E2,
    unsigned* __restrict__ bk2, int cap2, int nw2, int* __restrict__ wc2)
{
    __shared__ int lcnt[256];
    __shared__ int lbase[256];
    int nb0 = (E0 + PCHUNK - 1) / PCHUNK;
    int nb1 = (E1 + PCHUNK - 1) / PCHUNK;
    int b = blockIdx.x;
    const int* src; const int* dst; int E; unsigned* bk; int cap; int nw; int* wc; int chunk;
    if (b < nb0)            { src = src0; dst = dst0; E = E0; bk = bk0; cap = cap0; nw = nw0; wc = wc0; chunk = b; }
    else if (b < nb0 + nb1) { src = src1; dst = dst1; E = E1; bk = bk1; cap = cap1; nw = nw1; wc = wc1; chunk = b - nb0; }
    else                    { src = src2; dst = dst2; E = E2; bk = bk2; cap = cap2; nw = nw2; wc = wc2; chunk = b - nb0 - nb1; }
    int e0 = chunk * PCHUNK;
    int e1 = e0 + PCHUNK; if (e1 > E) e1 = E;
    for (int i = threadIdx.x; i < nw; i += 256) lcnt[i] = 0;
    __syncthreads();
    for (int e = e0 + threadIdx.x; e < e1; e += 256)
        atomicAdd(&lcnt[((unsigned)ntl(dst + e)) >> PWBITS], 1);
    __syncthreads();
    for (int i = threadIdx.x; i < nw; i += 256) {
        int c = lcnt[i];
        lbase[i] = (c > 0) ? atomicAdd(&wc[i], c) : 0;
        lcnt[i] = 0;
    }
    __syncthreads();
    for (int e = e0 + threadIdx.x; e < e1; e += 256) {
        int d = ntl(dst + e);
        int w = ((unsigned)d) >> PWBITS;
        int off = lbase[w] + atomicAdd(&lcnt[w], 1);
        if (off < cap)
            bk[(size_t)w * cap + off] =
                (((unsigned)(d & (PWIN - 1))) << 18) | (unsigned)ntl(src + e);
    }
}

// one launch, one 256-thread block per window across all 3 relations:
// LDS hist -> cnt out -> LDS exclusive scan -> rs out -> csr via LDS atomics.
__global__ __launch_bounds__(256)
void fill_win3(
    const unsigned* __restrict__ bk0, const int* __restrict__ wc0, int cap0,
    int* __restrict__ csr0, int* __restrict__ cnt0, int* __restrict__ rs0, int N0, int nw0,
    const unsigned* __restrict__ bk1, const int* __restrict__ wc1, int cap1,
    int* __restrict__ csr1, int* __restrict__ cnt1, int* __restrict__ rs1, int N1, int nw1,
    const unsigned* __restrict__ bk2, const int* __restrict__ wc2, int cap2,
    int* __restrict__ csr2, int* __restrict__ cnt2, int* __restrict__ rs2, int N2, int nw2)
{
    __shared__ int lc[PWIN];
    __shared__ int wsum[4], wpre[4];
    int b = blockIdx.x;
    const unsigned* bk; const int* wc; int cap; int* csr; int* cnt; int* rs; int N; int w;
    if (b < nw0)            { bk = bk0; wc = wc0; cap = cap0; csr = csr0; cnt = cnt0; rs = rs0; N = N0; w = b; }
    else if (b < nw0 + nw1) { bk = bk1; wc = wc1; cap = cap1; csr = csr1; cnt = cnt1; rs = rs1; N = N1; w = b - nw0; }
    else                    { bk = bk2; wc = wc2; cap = cap2; csr = csr2; cnt = cnt2; rs = rs2; N = N2; w = b - nw0 - nw1; }
    int d0 = w << PWBITS;
    int sz = wc[w]; if (sz > cap) sz = cap;
    const unsigned* bkt = bk + (size_t)w * cap;
    for (int i = threadIdx.x; i < PWIN; i += 256) lc[i] = 0;
    __syncthreads();
    for (int i = threadIdx.x; i < sz; i += 256)
        atomicAdd(&lc[ntlu(bkt + i) >> 18], 1);
    __syncthreads();
    for (int i = threadIdx.x; i < PWIN; i += 256) {
        int d = d0 + i;
        if (d < N) cnt[d] = lc[i];
    }
    __syncthreads();
    // exclusive scan of lc[1024], 4 elems/thread, base = w*cap
    int bi = threadIdx.x * 4;
    int v[4]; int ts = 0;
#pragma unroll
    for (int k = 0; k < 4; ++k) { v[k] = lc[bi + k]; ts += v[k]; }
    int lane = threadIdx.x & 63;
    int wid = threadIdx.x >> 6;
    int incl = ts;
#pragma unroll
    for (int off = 1; off < 64; off <<= 1) {
        int o = __shfl_up(incl, off);
        if (lane >= off) incl += o;
    }
    if (lane == 63) wsum[wid] = incl;
    __syncthreads();
    if (threadIdx.x == 0) {
        int r = 0;
        for (int i = 0; i < 4; ++i) { wpre[i] = r; r += wsum[i]; }
    }
    __syncthreads();
    int run = w * cap + wpre[wid] + (incl - ts);
#pragma unroll
    for (int k = 0; k < 4; ++k) {
        int d = d0 + bi + k;
        lc[bi + k] = run;
        if (d < N) rs[d] = run;
        run += v[k];
    }
    __syncthreads();
    for (int i = threadIdx.x; i < sz; i += 256) {
        unsigned u = ntlu(bkt + i);
        int pos = atomicAdd(&lc[u >> 18], 1);
        csr[pos] = (int)(u & 0x3FFFFu);
    }
}

// paper projection: h_pp, h_pa (bf16 neighbor features) + root_p (f32, incl bias)
__global__ void proj_paper(const float* __restrict__ x, const float* __restrict__ Wc,
                           const float* __restrict__ bias,
                           ushort_t* __restrict__ h_pp, ushort_t* __restrict__ h_pa,
                           float* __restrict__ root_p, int N)
{
    __shared__ float Wlds[64 * 96];
    __shared__ float blds[32];
    for (int i = threadIdx.x; i < 64 * 96; i += 256) Wlds[i] = Wc[i];
    if (threadIdx.x < 32) blds[threadIdx.x] = bias[threadIdx.x];
    __syncthreads();
    int n = blockIdx.x * 8 + (threadIdx.x >> 5);
    int c = threadIdx.x & 31;
    if (n < N) {
        const float* xr = x + (size_t)n * 64;
        float a0 = 0.f, a1 = 0.f, a2 = 0.f;
#pragma unroll
        for (int i = 0; i < 64; ++i) {
            float xv = xr[i];
            a0 += xv * Wlds[i * 96 + c];
            a1 += xv * Wlds[i * 96 + 32 + c];
            a2 += xv * Wlds[i * 96 + 64 + c];
        }
        h_pp[(size_t)n * 32 + c] = f2bf(a0);
        h_pa[(size_t)n * 32 + c] = f2bf(a1);
        root_p[(size_t)n * 32 + c] = a2 + blds[c];
    }
}

__global__ void proj_author(const float* __restrict__ x, const float* __restrict__ Wc,
                            const float* __restrict__ bias,
                            ushort_t* __restrict__ h_ap, float* __restrict__ root_a, int N)
{
    __shared__ float Wlds[64 * 64];
    __shared__ float blds[32];
    for (int i = threadIdx.x; i < 64 * 64; i += 256) Wlds[i] = Wc[i];
    if (threadIdx.x < 32) blds[threadIdx.x] = bias[threadIdx.x];
    __syncthreads();
    int n = blockIdx.x * 8 + (threadIdx.x >> 5);
    int c = threadIdx.x & 31;
    if (n < N) {
        const float* xr = x + (size_t)n * 64;
        float a0 = 0.f, a1 = 0.f;
#pragma unroll
        for (int i = 0; i < 64; ++i) {
            float xv = xr[i];
            a0 += xv * Wlds[i * 64 + c];
            a1 += xv * Wlds[i * 64 + 32 + c];
        }
        h_ap[(size_t)n * 32 + c] = f2bf(a0);
        root_a[(size_t)n * 32 + c] = a1 + blds[c];
    }
}

// 16 lanes/node, 2 cols/lane, tiny LDS, high occupancy. Unroll-4 independent
// gathers; fuses mean + root + relu + layer-2 dot products.
__global__ __launch_bounds__(256, 8)
void pull_paper(const ushort_t* __restrict__ h_pp, const ushort_t* __restrict__ h_ap,
                const float* __restrict__ root,
                const int* __restrict__ csr_pp, const int* __restrict__ rs_pp,
                const int* __restrict__ cnt_pp,
                const int* __restrict__ csr_ap, const int* __restrict__ rs_ap,
                const int* __restrict__ cnt_ap,
                const float* __restrict__ vv,
                float* __restrict__ s_pp, float* __restrict__ out, int N)
{
    __shared__ float v0[32], v1[32];
    __shared__ float c2s;
    if (threadIdx.x < 32) { v0[threadIdx.x] = vv[threadIdx.x]; v1[threadIdx.x] = vv[32 + threadIdx.x]; }
    if (threadIdx.x == 0) c2s = vv[64];
    __syncthreads();
    int n = blockIdx.x * 16 + (threadIdx.x >> 4);
    if (n >= N) return;
    int c = threadIdx.x & 15;
    const ushort_t* hpp_c = h_pp + 2 * c;
    const ushort_t* hap_c = h_ap + 2 * c;
    int s1 = rs_pp[n], k1 = cnt_pp[n], e1 = s1 + k1;
    float a0 = 0.f, a1 = 0.f;
    int j = s1;
    for (; j + 4 <= e1; j += 4) {
        int i0 = ntl(csr_pp + j), i1 = ntl(csr_pp + j + 1);
        int i2 = ntl(csr_pp + j + 2), i3 = ntl(csr_pp + j + 3);
        unsigned u0 = *(const unsigned*)(hpp_c + (size_t)i0 * 32);
        unsigned u1 = *(const unsigned*)(hpp_c + (size_t)i1 * 32);
        unsigned u2 = *(const unsigned*)(hpp_c + (size_t)i2 * 32);
        unsigned u3 = *(const unsigned*)(hpp_c + (size_t)i3 * 32);
        a0 += (bf2f_lo(u0) + bf2f_lo(u1)) + (bf2f_lo(u2) + bf2f_lo(u3));
        a1 += (bf2f_hi(u0) + bf2f_hi(u1)) + (bf2f_hi(u2) + bf2f_hi(u3));
    }
    for (; j < e1; ++j) {
        unsigned u0 = *(const unsigned*)(hpp_c + (size_t)ntl(csr_pp + j) * 32);
        a0 += bf2f_lo(u0); a1 += bf2f_hi(u0);
    }
    int s2 = rs_ap[n], k2 = cnt_ap[n], e2 = s2 + k2;
    float b0 = 0.f, b1 = 0.f;
    j = s2;
    for (; j + 4 <= e2; j += 4) {
        int i0 = ntl(csr_ap + j), i1 = ntl(csr_ap + j + 1);
        int i2 = ntl(csr_ap + j + 2), i3 = ntl(csr_ap + j + 3);
        unsigned u0 = *(const unsigned*)(hap_c + (size_t)i0 * 32);
        unsigned u1 = *(const unsigned*)(hap_c + (size_t)i1 * 32);
        unsigned u2 = *(const unsigned*)(hap_c + (size_t)i2 * 32);
        unsigned u3 = *(const unsigned*)(hap_c + (size_t)i3 * 32);
        b0 += (bf2f_lo(u0) + bf2f_lo(u1)) + (bf2f_lo(u2) + bf2f_lo(u3));
        b1 += (bf2f_hi(u0) + bf2f_hi(u1)) + (bf2f_hi(u2) + bf2f_hi(u3));
    }
    for (; j < e2; ++j) {
        unsigned u0 = *(const unsigned*)(hap_c + (size_t)ntl(csr_ap + j) * 32);
        b0 += bf2f_lo(u0); b1 += bf2f_hi(u0);
    }
    float ipp = 1.0f / fmaxf((float)k1, 1.0f);
    float iap = 1.0f / fmaxf((float)k2, 1.0f);
    float p0 = fmaxf(root[(size_t)n * 32 + 2 * c]     + a0 * ipp + b0 * iap, 0.f);
    float p1 = fmaxf(root[(size_t)n * 32 + 2 * c + 1] + a1 * ipp + b1 * iap, 0.f);
    float d0 = p0 * v0[2 * c] + p1 * v0[2 * c + 1];
    float d1 = p0 * v1[2 * c] + p1 * v1[2 * c + 1];
#pragma unroll
    for (int off = 1; off < 16; off <<= 1) {
        d0 += __shfl_xor(d0, off);
        d1 += __shfl_xor(d1, off);
    }
    if (c == 0) { s_pp[n] = d0; out[n] = d1 + c2s; }
}

__global__ __launch_bounds__(256, 8)
void pull_author(const ushort_t* __restrict__ h_pa, const float* __restrict__ root,
                 const int* __restrict__ csr_pa, const int* __restrict__ rs_pa,
                 const int* __restrict__ cnt_pa,
                 const float* __restrict__ vv, float* __restrict__ s_ap, int N)
{
    __shared__ float v0[32];
    if (threadIdx.x < 32) v0[threadIdx.x] = vv[96 + threadIdx.x];
    __syncthreads();
    int n = blockIdx.x * 16 + (threadIdx.x >> 4);
    if (n >= N) return;
    int c = threadIdx.x & 15;
    const ushort_t* hpa_c = h_pa + 2 * c;
    int s1 = rs_pa[n], k1 = cnt_pa[n], e1 = s1 + k1;
    float a0 = 0.f, a1 = 0.f;
    int j = s1;
    for (; j + 4 <= e1; j += 4) {
        int i0 = ntl(csr_pa + j), i1 = ntl(csr_pa + j + 1);
        int i2 = ntl(csr_pa + j + 2), i3 = ntl(csr_pa + j + 3);
        unsigned u0 = *(const unsigned*)(hpa_c + (size_t)i0 * 32);
        unsigned u1 = *(const unsigned*)(hpa_c + (size_t)i1 * 32);
        unsigned u2 = *(const unsigned*)(hpa_c + (size_t)i2 * 32);
        unsigned u3 = *(const unsigned*)(hpa_c + (size_t)i3 * 32);
        a0 += (bf2f_lo(u0) + bf2f_lo(u1)) + (bf2f_lo(u2) + bf2f_lo(u3));
        a1 += (bf2f_hi(u0) + bf2f_hi(u1)) + (bf2f_hi(u2) + bf2f_hi(u3));
    }
    for (; j < e1; ++j) {
        unsigned u0 = *(const unsigned*)(hpa_c + (size_t)ntl(csr_pa + j) * 32);
        a0 += bf2f_lo(u0); a1 += bf2f_hi(u0);
    }
    float ip = 1.0f / fmaxf((float)k1, 1.0f);
    float p0 = fmaxf(root[(size_t)n * 32 + 2 * c]     + a0 * ip, 0.f);
    float p1 = fmaxf(root[(size_t)n * 32 + 2 * c + 1] + a1 * ip, 0.f);
    float d0 = p0 * v0[2 * c] + p1 * v0[2 * c + 1];
#pragma unroll
    for (int off = 1; off < 16; off <<= 1) d0 += __shfl_xor(d0, off);
    if (c == 0) s_ap[n] = d0;
}

// layer-2 scalar pull, 4 lanes/node.
__global__ __launch_bounds__(256, 8)
void pull2(const float* __restrict__ s_pp, const float* __restrict__ s_ap,
           const int* __restrict__ csr_pp, const int* __restrict__ rs_pp,
           const int* __restrict__ cnt_pp,
           const int* __restrict__ csr_ap, const int* __restrict__ rs_ap,
           const int* __restrict__ cnt_ap,
           float* __restrict__ out, int N)
{
    int g = (blockIdx.x * blockDim.x + threadIdx.x) >> 2;
    int c = threadIdx.x & 3;
    if (g >= N) return;
    int s1 = rs_pp[g], k1 = cnt_pp[g], e1 = s1 + k1;
    float t = 0.f;
    for (int j = s1 + c; j < e1; j += 4) t += s_pp[ntl(csr_pp + j)];
    int s2 = rs_ap[g], k2 = cnt_ap[g], e2 = s2 + k2;
    float u = 0.f;
    for (int j = s2 + c; j < e2; j += 4) u += s_ap[ntl(csr_ap + j)];
    t += __shfl_xor(t, 1); t += __shfl_xor(t, 2);
    u += __shfl_xor(u, 1); u += __shfl_xor(u, 2);
    if (c == 0) {
        out[g] += t / fmaxf((float)k1, 1.f) + u / fmaxf((float)k2, 1.f);
    }
}

extern "C" void kernel_launch(void* const* d_in, const int* in_sizes, int n_in,
                              void* d_out, int out_size, void* d_ws, size_t ws_size,
                              hipStream_t stream)
{
    const float* x_paper  = (const float*)d_in[0];
    const float* x_author = (const float*)d_in[1];
    const int* src_pp = (const int*)d_in[2];
    const int* dst_pp = (const int*)d_in[3];
    const int* src_ap = (const int*)d_in[4];
    const int* dst_ap = (const int*)d_in[5];
    const int* src_pa = (const int*)d_in[6];
    const int* dst_pa = (const int*)d_in[7];
    const float* Wl1_pp = (const float*)d_in[8];
    const float* bl1_pp = (const float*)d_in[9];
    const float* Wr1_pp = (const float*)d_in[10];
    const float* Wl1_ap = (const float*)d_in[11];
    const float* bl1_ap = (const float*)d_in[12];
    const float* Wr1_ap = (const float*)d_in[13];
    const float* Wl1_pa = (const float*)d_in[14];
    const float* bl1_pa = (const float*)d_in[15];
    const float* Wr1_pa = (const float*)d_in[16];
    const float* Wl2_pp = (const float*)d_in[17];
    const float* bl2_pp = (const float*)d_in[18];
    const float* Wr2_pp = (const float*)d_in[19];
    const float* Wl2_ap = (const float*)d_in[20];
    const float* bl2_ap = (const float*)d_in[21];
    const float* Wr2_ap = (const float*)d_in[22];
    const float* W_lin  = (const float*)d_in[23];
    const float* b_lin  = (const float*)d_in[24];

    const int NP = in_sizes[0] / 64;
    const int NA = in_sizes[1] / 64;
    const int E_PP = in_sizes[2];
    const int E_AP = in_sizes[4];
    const int E_PA = in_sizes[6];

    const int nw_pp = (NP + PWIN - 1) >> PWBITS;   // 196
    const int nw_ap = nw_pp;                       // 196
    const int nw_pa = (NA + PWIN - 1) >> PWBITS;   // 98
    const int cap_pp = E_PP / nw_pp + CAPPAD;
    const int cap_ap = E_AP / nw_ap + CAPPAD;
    const int cap_pa = E_PA / nw_pa + CAPPAD;

    // ---- workspace ----
    char* wp = (char*)d_ws;
    int* wcur = (int*)wp;             wp += 768 * 4;   // 3 x 256, zeroed
    unsigned* bk_pp = (unsigned*)wp;  wp += (size_t)nw_pp * cap_pp * 4;
    unsigned* bk_ap = (unsigned*)wp;  wp += (size_t)nw_ap * cap_ap * 4;
    unsigned* bk_pa = (unsigned*)wp;  wp += (size_t)nw_pa * cap_pa * 4;
    int* csr_pp = (int*)wp;           wp += (size_t)nw_pp * cap_pp * 4;
    int* csr_ap = (int*)wp;           wp += (size_t)nw_ap * cap_ap * 4;
    int* csr_pa = (int*)wp;           wp += (size_t)nw_pa * cap_pa * 4;
    int* cnt    = (int*)wp;           wp += (size_t)(2 * NP + NA) * 4;
    int* rs     = (int*)wp;           wp += (size_t)(2 * NP + NA) * 4;
    ushort_t* h_pp = (ushort_t*)wp;   wp += (size_t)NP * 32 * 2;
    ushort_t* h_pa = (ushort_t*)wp;   wp += (size_t)NP * 32 * 2;
    ushort_t* h_ap = (ushort_t*)wp;   wp += (size_t)NA * 32 * 2;
    float* root_a = (float*)wp;       wp += (size_t)NA * 32 * 4;
    float* s_pp   = (float*)wp;       wp += (size_t)NP * 4;
    float* s_ap   = (float*)wp;       wp += (size_t)NA * 4;
    float* Wcomb_p = (float*)wp;      wp += 64 * 96 * 4;
    float* Wcomb_a = (float*)wp;      wp += 64 * 64 * 4;
    float* bias_p = (float*)wp;       wp += 32 * 4;
    float* bias_a = (float*)wp;       wp += 32 * 4;
    float* vv     = (float*)wp;       wp += 128 * 4;
    // root_p overlays the (dead after fill_win3) bucket region bk_pp..bk_ap
    float* root_p = (float*)bk_pp;    // NP*32*4 = 25.6MB <= bk_pp+bk_ap ~25.6MB

    int* cnt_pp = cnt,  * cnt_ap = cnt + NP,  * cnt_pa = cnt + 2 * NP;
    int* rs_pp  = rs,   * rs_ap  = rs + NP,   * rs_pa  = rs + 2 * NP;

    float* out = (float*)d_out;

    // zero the window cursors only
    hipMemsetAsync(wcur, 0, 768 * sizeof(int), stream);

    prep_weights<<<1, 256, 0, stream>>>(
        Wl1_pp, Wr1_pp, Wl1_ap, Wr1_ap, Wl1_pa, Wr1_pa,
        bl1_pp, bl1_ap, bl1_pa,
        Wl2_pp, bl2_pp, Wr2_pp, Wl2_ap, bl2_ap, Wr2_ap,
        W_lin, b_lin, Wcomb_p, Wcomb_a, bias_p, bias_a, vv);

    int nb_total = (E_PP + PCHUNK - 1) / PCHUNK + (E_AP + PCHUNK - 1) / PCHUNK
                 + (E_PA + PCHUNK - 1) / PCHUNK;
    partition3<<<nb_total, 256, 0, stream>>>(
        src_pp, dst_pp, E_PP, bk_pp, cap_pp, nw_pp, wcur + 0,
        src_ap, dst_ap, E_AP, bk_ap, cap_ap, nw_ap, wcur + 256,
        src_pa, dst_pa, E_PA, bk_pa, cap_pa, nw_pa, wcur + 512);

    fill_win3<<<nw_pp + nw_ap + nw_pa, 256, 0, stream>>>(
        bk_pp, wcur + 0,   cap_pp, csr_pp, cnt_pp, rs_pp, NP, nw_pp,
        bk_ap, wcur + 256, cap_ap, csr_ap, cnt_ap, rs_ap, NP, nw_ap,
        bk_pa, wcur + 512, cap_pa, csr_pa, cnt_pa, rs_pa, NA, nw_pa);

    proj_paper<<<(NP + 7) / 8, 256, 0, stream>>>(x_paper, Wcomb_p, bias_p, h_pp, h_pa, root_p, NP);
    proj_author<<<(NA + 7) / 8, 256, 0, stream>>>(x_author, Wcomb_a, bias_a, h_ap, root_a, NA);

    pull_paper<<<(NP + 15) / 16, 256, 0, stream>>>(
        h_pp, h_ap, root_p, csr_pp, rs_pp, cnt_pp, csr_ap, rs_ap, cnt_ap,
        vv, s_pp, out, NP);
    pull_author<<<(NA + 15) / 16, 256, 0, stream>>>(
        h_pa, root_a, csr_pa, rs_pa, cnt_pa, vv, s_ap, NA);

    pull2<<<((size_t)NP * 4 + 255) / 256, 256, 0, stream>>>(
        s_pp, s_ap, csr_pp, rs_pp, cnt_pp, csr_ap, rs_ap, cnt_ap, out, NP);
}

// Round 12
// 448.844 us; speedup vs baseline: 2.2844x; 1.2078x over previous
//
#include <hip/hip_runtime.h>

// ---------------------------------------------------------------------------
// HeteroSAGE: CSR pull; CSR built with ZERO per-edge global atomics.
//   partition3 -> fill_win3 (round-11, unchanged)
//   proj via MFMA 16x16x32 bf16: W pre-packed into B-frag layout by
//   prep_weights; A-frags straight from x (float4 -> bf16); bias as C-in.
//   pull (8 waves/EU, unroll-4 gathers) -> pull2 scalar layer-2.
// ---------------------------------------------------------------------------

typedef unsigned short ushort_t;
typedef __attribute__((ext_vector_type(8))) short bf16x8;
typedef __attribute__((ext_vector_type(4))) float f32x4;

#define PWBITS 10
#define PWIN   (1 << PWBITS)     // 1024 dsts per window
#define PCHUNK 8192              // edges per partition chunk
#define CAPPAD 4096              // bucket slack

__device__ inline ushort_t f2bf(float f) {
    unsigned u = __float_as_uint(f);
    unsigned r = (u + 0x7FFFu + ((u >> 16) & 1u)) >> 16;
    return (ushort_t)r;
}
__device__ inline float bf2f_lo(unsigned u) { return __uint_as_float(u << 16); }
__device__ inline float bf2f_hi(unsigned u) { return __uint_as_float(u & 0xFFFF0000u); }
__device__ inline int ntl(const int* p) { return __builtin_nontemporal_load(p); }
__device__ inline unsigned ntlu(const unsigned* p) { return __builtin_nontemporal_load(p); }

__global__ void prep_weights(
    const float* __restrict__ Wl1_pp, const float* __restrict__ Wr1_pp,
    const float* __restrict__ Wl1_ap, const float* __restrict__ Wr1_ap,
    const float* __restrict__ Wl1_pa, const float* __restrict__ Wr1_pa,
    const float* __restrict__ bl1_pp, const float* __restrict__ bl1_ap,
    const float* __restrict__ bl1_pa,
    const float* __restrict__ Wl2_pp, const float* __restrict__ bl2_pp,
    const float* __restrict__ Wr2_pp,
    const float* __restrict__ Wl2_ap, const float* __restrict__ bl2_ap,
    const float* __restrict__ Wr2_ap,
    const float* __restrict__ W_lin, const float* __restrict__ b_lin,
    float* __restrict__ Wcomb_p,   // 64 x 96: [Wl1_pp | Wl1_pa | Wr1_pp+Wr1_ap]
    float* __restrict__ Wcomb_a,   // 64 x 64: [Wl1_ap | Wr1_pa]
    ushort_t* __restrict__ Wfrag_p, // 12 frags x 64 lanes x 8 bf16 (B-frag layout)
    ushort_t* __restrict__ Wfrag_a, // 8 frags x 64 lanes x 8
    float* __restrict__ bias_p,    // 32
    float* __restrict__ bias_a,    // 32
    float* __restrict__ vv)        // [0:32) v_pp [32:64) v_r [64] c2 [96:128) v_ap
{
    int t = threadIdx.x;
    for (int idx = t; idx < 64 * 96; idx += 256) {
        int i = idx / 96, j = idx % 96;
        float v;
        if (j < 32)       v = Wl1_pp[i * 32 + j];
        else if (j < 64)  v = Wl1_pa[i * 32 + (j - 32)];
        else              v = Wr1_pp[i * 32 + (j - 64)] + Wr1_ap[i * 32 + (j - 64)];
        Wcomb_p[idx] = v;
    }
    for (int idx = t; idx < 64 * 64; idx += 256) {
        int i = idx / 64, j = idx % 64;
        Wcomb_a[idx] = (j < 32) ? Wl1_ap[i * 32 + j] : Wr1_pa[i * 32 + (j - 32)];
    }
    if (t < 32) {
        bias_p[t] = bl1_pp[t] + bl1_ap[t];
        bias_a[t] = bl1_pa[t];
        float vpp = 0.f, vr = 0.f, vap = 0.f;
        for (int j = 0; j < 32; ++j) {
            float wl = W_lin[j];
            vpp += Wl2_pp[t * 32 + j] * wl;
            vr  += (Wr2_pp[t * 32 + j] + Wr2_ap[t * 32 + j]) * wl;
            vap += Wl2_ap[t * 32 + j] * wl;
        }
        vv[t] = vpp; vv[32 + t] = vr; vv[96 + t] = vap;
    }
    if (t == 0) {
        float c = b_lin[0];
        for (int j = 0; j < 32; ++j) c += (bl2_pp[j] + bl2_ap[j]) * W_lin[j];
        vv[64] = c;
    }
    __syncthreads();
    // B-fragment packing for mfma_f32_16x16x32_bf16:
    // frag f = nt*2+kh; lane l, elem j -> B[k][n] with
    // k = kh*32 + 8*(l>>4) + j, n = nt*16 + (l&15).
    for (int idx = t; idx < 12 * 64 * 8; idx += 256) {
        int f = idx >> 9, l = (idx >> 3) & 63, j = idx & 7;
        int nt = f >> 1, kh = f & 1;
        int k = kh * 32 + 8 * (l >> 4) + j;
        int n = nt * 16 + (l & 15);
        Wfrag_p[idx] = f2bf(Wcomb_p[k * 96 + n]);
    }
    for (int idx = t; idx < 8 * 64 * 8; idx += 256) {
        int f = idx >> 9, l = (idx >> 3) & 63, j = idx & 7;
        int nt = f >> 1, kh = f & 1;
        int k = kh * 32 + 8 * (l >> 4) + j;
        int n = nt * 16 + (l & 15);
        Wfrag_a[idx] = f2bf(Wcomb_a[k * 64 + n]);
    }
}

// one launch, all 3 relations: group edges by dst-window via LDS counts +
// claimed contiguous bucket runs; packed coalesced writes.
__global__ __launch_bounds__(256)
void partition3(
    const int* __restrict__ src0, const int* __restrict__ dst0, int E0,
    unsigned* __restrict__ bk0, int cap0, int nw0, int* __restrict__ wc0,
    const int* __restrict__ src1, const int* __restrict__ dst1, int E1,
    unsigned* __restrict__ bk1, int cap1, int nw1, int* __restrict__ wc1,
    const int* __restrict__ src2, const int* __restrict__ dst2, int E2,
    unsigned* __restrict__ bk2, int cap2, int nw2, int* __restrict__ wc2)
{
    __shared__ int lcnt[256];
    __shared__ int lbase[256];
    int nb0 = (E0 + PCHUNK - 1) / PCHUNK;
    int nb1 = (E1 + PCHUNK - 1) / PCHUNK;
    int b = blockIdx.x;
    const int* src; const int* dst; int E; unsigned* bk; int cap; int nw; int* wc; int chunk;
    if (b < nb0)            { src = src0; dst = dst0; E = E0; bk = bk0; cap = cap0; nw = nw0; wc = wc0; chunk = b; }
    else if (b < nb0 + nb1) { src = src1; dst = dst1; E = E1; bk = bk1; cap = cap1; nw = nw1; wc = wc1; chunk = b - nb0; }
    else                    { src = src2; dst = dst2; E = E2; bk = bk2; cap = cap2; nw = nw2; wc = wc2; chunk = b - nb0 - nb1; }
    int e0 = chunk * PCHUNK;
    int e1 = e0 + PCHUNK; if (e1 > E) e1 = E;
    for (int i = threadIdx.x; i < nw; i += 256) lcnt[i] = 0;
    __syncthreads();
    for (int e = e0 + threadIdx.x; e < e1; e += 256)
        atomicAdd(&lcnt[((unsigned)ntl(dst + e)) >> PWBITS], 1);
    __syncthreads();
    for (int i = threadIdx.x; i < nw; i += 256) {
        int c = lcnt[i];
        lbase[i] = (c > 0) ? atomicAdd(&wc[i], c) : 0;
        lcnt[i] = 0;
    }
    __syncthreads();
    for (int e = e0 + threadIdx.x; e < e1; e += 256) {
        int d = ntl(dst + e);
        int w = ((unsigned)d) >> PWBITS;
        int off = lbase[w] + atomicAdd(&lcnt[w], 1);
        if (off < cap)
            bk[(size_t)w * cap + off] =
                (((unsigned)(d & (PWIN - 1))) << 18) | (unsigned)ntl(src + e);
    }
}

// one launch, one 256-thread block per window across all 3 relations.
__global__ __launch_bounds__(256)
void fill_win3(
    const unsigned* __restrict__ bk0, const int* __restrict__ wc0, int cap0,
    int* __restrict__ csr0, int* __restrict__ cnt0, int* __restrict__ rs0, int N0, int nw0,
    const unsigned* __restrict__ bk1, const int* __restrict__ wc1, int cap1,
    int* __restrict__ csr1, int* __restrict__ cnt1, int* __restrict__ rs1, int N1, int nw1,
    const unsigned* __restrict__ bk2, const int* __restrict__ wc2, int cap2,
    int* __restrict__ csr2, int* __restrict__ cnt2, int* __restrict__ rs2, int N2, int nw2)
{
    __shared__ int lc[PWIN];
    __shared__ int wsum[4], wpre[4];
    int b = blockIdx.x;
    const unsigned* bk; const int* wc; int cap; int* csr; int* cnt; int* rs; int N; int w;
    if (b < nw0)            { bk = bk0; wc = wc0; cap = cap0; csr = csr0; cnt = cnt0; rs = rs0; N = N0; w = b; }
    else if (b < nw0 + nw1) { bk = bk1; wc = wc1; cap = cap1; csr = csr1; cnt = cnt1; rs = rs1; N = N1; w = b - nw0; }
    else                    { bk = bk2; wc = wc2; cap = cap2; csr = csr2; cnt = cnt2; rs = rs2; N = N2; w = b - nw0 - nw1; }
    int d0 = w << PWBITS;
    int sz = wc[w]; if (sz > cap) sz = cap;
    const unsigned* bkt = bk + (size_t)w * cap;
    for (int i = threadIdx.x; i < PWIN; i += 256) lc[i] = 0;
    __syncthreads();
    for (int i = threadIdx.x; i < sz; i += 256)
        atomicAdd(&lc[ntlu(bkt + i) >> 18], 1);
    __syncthreads();
    for (int i = threadIdx.x; i < PWIN; i += 256) {
        int d = d0 + i;
        if (d < N) cnt[d] = lc[i];
    }
    __syncthreads();
    int bi = threadIdx.x * 4;
    int v[4]; int ts = 0;
#pragma unroll
    for (int k = 0; k < 4; ++k) { v[k] = lc[bi + k]; ts += v[k]; }
    int lane = threadIdx.x & 63;
    int wid = threadIdx.x >> 6;
    int incl = ts;
#pragma unroll
    for (int off = 1; off < 64; off <<= 1) {
        int o = __shfl_up(incl, off);
        if (lane >= off) incl += o;
    }
    if (lane == 63) wsum[wid] = incl;
    __syncthreads();
    if (threadIdx.x == 0) {
        int r = 0;
        for (int i = 0; i < 4; ++i) { wpre[i] = r; r += wsum[i]; }
    }
    __syncthreads();
    int run = w * cap + wpre[wid] + (incl - ts);
#pragma unroll
    for (int k = 0; k < 4; ++k) {
        int d = d0 + bi + k;
        lc[bi + k] = run;
        if (d < N) rs[d] = run;
        run += v[k];
    }
    __syncthreads();
    for (int i = threadIdx.x; i < sz; i += 256) {
        unsigned u = ntlu(bkt + i);
        int pos = atomicAdd(&lc[u >> 18], 1);
        csr[pos] = (int)(u & 0x3FFFFu);
    }
}

__device__ inline bf16x8 cvt8(const float* p) {
    float4 a = *(const float4*)p;
    float4 b = *(const float4*)(p + 4);
    bf16x8 r;
    r[0] = (short)f2bf(a.x); r[1] = (short)f2bf(a.y);
    r[2] = (short)f2bf(a.z); r[3] = (short)f2bf(a.w);
    r[4] = (short)f2bf(b.x); r[5] = (short)f2bf(b.y);
    r[6] = (short)f2bf(b.z); r[7] = (short)f2bf(b.w);
    return r;
}

// MFMA projection, paper: 4 waves x 16 nodes = 64 nodes/block; 6 N-tiles.
__global__ __launch_bounds__(256)
void proj_paper_mfma(const float* __restrict__ x, const ushort_t* __restrict__ Wfrag,
                     const float* __restrict__ bias,
                     ushort_t* __restrict__ h_pp, ushort_t* __restrict__ h_pa,
                     float* __restrict__ root_p, int N)
{
    int wave = threadIdx.x >> 6, lane = threadIdx.x & 63;
    int mbase = blockIdx.x * 64 + wave * 16;
    int row = lane & 15, grp = lane >> 4;
    int nA = mbase + row; if (nA > N - 1) nA = N - 1;
    const float* xr = x + (size_t)nA * 64 + grp * 8;
    bf16x8 a0 = cvt8(xr);        // k = grp*8 + j
    bf16x8 a1 = cvt8(xr + 32);   // k = 32 + grp*8 + j
    float bval = bias[grp >= 2 ? 0 : 0];  // placeholder, real init below
    f32x4 acc0 = {0.f, 0.f, 0.f, 0.f}, acc1 = acc0, acc2 = acc0, acc3 = acc0;
    float bp0 = bias[row];        // nt=4: col=row -> bias[col]
    float bp1 = bias[16 + row];   // nt=5
    f32x4 acc4 = {bp0, bp0, bp0, bp0};
    f32x4 acc5 = {bp1, bp1, bp1, bp1};
    const bf16x8* wf = (const bf16x8*)(Wfrag) + lane;  // frag f at wf[f*64]
    acc0 = __builtin_amdgcn_mfma_f32_16x16x32_bf16(a0, wf[0 * 64], acc0, 0, 0, 0);
    acc0 = __builtin_amdgcn_mfma_f32_16x16x32_bf16(a1, wf[1 * 64], acc0, 0, 0, 0);
    acc1 = __builtin_amdgcn_mfma_f32_16x16x32_bf16(a0, wf[2 * 64], acc1, 0, 0, 0);
    acc1 = __builtin_amdgcn_mfma_f32_16x16x32_bf16(a1, wf[3 * 64], acc1, 0, 0, 0);
    acc2 = __builtin_amdgcn_mfma_f32_16x16x32_bf16(a0, wf[4 * 64], acc2, 0, 0, 0);
    acc2 = __builtin_amdgcn_mfma_f32_16x16x32_bf16(a1, wf[5 * 64], acc2, 0, 0, 0);
    acc3 = __builtin_amdgcn_mfma_f32_16x16x32_bf16(a0, wf[6 * 64], acc3, 0, 0, 0);
    acc3 = __builtin_amdgcn_mfma_f32_16x16x32_bf16(a1, wf[7 * 64], acc3, 0, 0, 0);
    acc4 = __builtin_amdgcn_mfma_f32_16x16x32_bf16(a0, wf[8 * 64], acc4, 0, 0, 0);
    acc4 = __builtin_amdgcn_mfma_f32_16x16x32_bf16(a1, wf[9 * 64], acc4, 0, 0, 0);
    acc5 = __builtin_amdgcn_mfma_f32_16x16x32_bf16(a0, wf[10 * 64], acc5, 0, 0, 0);
    acc5 = __builtin_amdgcn_mfma_f32_16x16x32_bf16(a1, wf[11 * 64], acc5, 0, 0, 0);
    // C layout: col = lane&15 (=row var), out-node = mbase + grp*4 + reg
    int col = row;
    int node0 = mbase + grp * 4;
#pragma unroll
    for (int reg = 0; reg < 4; ++reg) {
        int nd = node0 + reg;
        if (nd < N) {
            size_t b32 = (size_t)nd * 32;
            h_pp[b32 + col]        = f2bf(acc0[reg]);
            h_pp[b32 + 16 + col]   = f2bf(acc1[reg]);
            h_pa[b32 + col]        = f2bf(acc2[reg]);
            h_pa[b32 + 16 + col]   = f2bf(acc3[reg]);
            root_p[b32 + col]      = acc4[reg];
            root_p[b32 + 16 + col] = acc5[reg];
        }
    }
}

// MFMA projection, author: 4 N-tiles.
__global__ __launch_bounds__(256)
void proj_author_mfma(const float* __restrict__ x, const ushort_t* __restrict__ Wfrag,
                      const float* __restrict__ bias,
                      ushort_t* __restrict__ h_ap, float* __restrict__ root_a, int N)
{
    int wave = threadIdx.x >> 6, lane = threadIdx.x & 63;
    int mbase = blockIdx.x * 64 + wave * 16;
    int row = lane & 15, grp = lane >> 4;
    int nA = mbase + row; if (nA > N - 1) nA = N - 1;
    const float* xr = x + (size_t)nA * 64 + grp * 8;
    bf16x8 a0 = cvt8(xr);
    bf16x8 a1 = cvt8(xr + 32);
    f32x4 acc0 = {0.f, 0.f, 0.f, 0.f}, acc1 = acc0;
    float bp0 = bias[row];
    float bp1 = bias[16 + row];
    f32x4 acc2 = {bp0, bp0, bp0, bp0};
    f32x4 acc3 = {bp1, bp1, bp1, bp1};
    const bf16x8* wf = (const bf16x8*)(Wfrag) + lane;
    acc0 = __builtin_amdgcn_mfma_f32_16x16x32_bf16(a0, wf[0 * 64], acc0, 0, 0, 0);
    acc0 = __builtin_amdgcn_mfma_f32_16x16x32_bf16(a1, wf[1 * 64], acc0, 0, 0, 0);
    acc1 = __builtin_amdgcn_mfma_f32_16x16x32_bf16(a0, wf[2 * 64], acc1, 0, 0, 0);
    acc1 = __builtin_amdgcn_mfma_f32_16x16x32_bf16(a1, wf[3 * 64], acc1, 0, 0, 0);
    acc2 = __builtin_amdgcn_mfma_f32_16x16x32_bf16(a0, wf[4 * 64], acc2, 0, 0, 0);
    acc2 = __builtin_amdgcn_mfma_f32_16x16x32_bf16(a1, wf[5 * 64], acc2, 0, 0, 0);
    acc3 = __builtin_amdgcn_mfma_f32_16x16x32_bf16(a0, wf[6 * 64], acc3, 0, 0, 0);
    acc3 = __builtin_amdgcn_mfma_f32_16x16x32_bf16(a1, wf[7 * 64], acc3, 0, 0, 0);
    int col = row;
    int node0 = mbase + grp * 4;
#pragma unroll
    for (int reg = 0; reg < 4; ++reg) {
        int nd = node0 + reg;
        if (nd < N) {
            size_t b32 = (size_t)nd * 32;
            h_ap[b32 + col]        = f2bf(acc0[reg]);
            h_ap[b32 + 16 + col]   = f2bf(acc1[reg]);
            root_a[b32 + col]      = acc2[reg];
            root_a[b32 + 16 + col] = acc3[reg];
        }
    }
}

// 16 lanes/node, 2 cols/lane, tiny LDS, high occupancy. Unroll-4 independent
// gathers; fuses mean + root + relu + layer-2 dot products.
__global__ __launch_bounds__(256, 8)
void pull_paper(const ushort_t* __restrict__ h_pp, const ushort_t* __restrict__ h_ap,
                const float* __restrict__ root,
                const int* __restrict__ csr_pp, const int* __restrict__ rs_pp,
                const int* __restrict__ cnt_pp,
                const int* __restrict__ csr_ap, const int* __restrict__ rs_ap,
                const int* __restrict__ cnt_ap,
                const float* __restrict__ vv,
                float* __restrict__ s_pp, float* __restrict__ out, int N)
{
    __shared__ float v0[32], v1[32];
    __shared__ float c2s;
    if (threadIdx.x < 32) { v0[threadIdx.x] = vv[threadIdx.x]; v1[threadIdx.x] = vv[32 + threadIdx.x]; }
    if (threadIdx.x == 0) c2s = vv[64];
    __syncthreads();
    int n = blockIdx.x * 16 + (threadIdx.x >> 4);
    if (n >= N) return;
    int c = threadIdx.x & 15;
    const ushort_t* hpp_c = h_pp + 2 * c;
    const ushort_t* hap_c = h_ap + 2 * c;
    int s1 = rs_pp[n], k1 = cnt_pp[n], e1 = s1 + k1;
    float a0 = 0.f, a1 = 0.f;
    int j = s1;
    for (; j + 4 <= e1; j += 4) {
        int i0 = ntl(csr_pp + j), i1 = ntl(csr_pp + j + 1);
        int i2 = ntl(csr_pp + j + 2), i3 = ntl(csr_pp + j + 3);
        unsigned u0 = *(const unsigned*)(hpp_c + (size_t)i0 * 32);
        unsigned u1 = *(const unsigned*)(hpp_c + (size_t)i1 * 32);
        unsigned u2 = *(const unsigned*)(hpp_c + (size_t)i2 * 32);
        unsigned u3 = *(const unsigned*)(hpp_c + (size_t)i3 * 32);
        a0 += (bf2f_lo(u0) + bf2f_lo(u1)) + (bf2f_lo(u2) + bf2f_lo(u3));
        a1 += (bf2f_hi(u0) + bf2f_hi(u1)) + (bf2f_hi(u2) + bf2f_hi(u3));
    }
    for (; j < e1; ++j) {
        unsigned u0 = *(const unsigned*)(hpp_c + (size_t)ntl(csr_pp + j) * 32);
        a0 += bf2f_lo(u0); a1 += bf2f_hi(u0);
    }
    int s2 = rs_ap[n], k2 = cnt_ap[n], e2 = s2 + k2;
    float b0 = 0.f, b1 = 0.f;
    j = s2;
    for (; j + 4 <= e2; j += 4) {
        int i0 = ntl(csr_ap + j), i1 = ntl(csr_ap + j + 1);
        int i2 = ntl(csr_ap + j + 2), i3 = ntl(csr_ap + j + 3);
        unsigned u0 = *(const unsigned*)(hap_c + (size_t)i0 * 32);
        unsigned u1 = *(const unsigned*)(hap_c + (size_t)i1 * 32);
        unsigned u2 = *(const unsigned*)(hap_c + (size_t)i2 * 32);
        unsigned u3 = *(const unsigned*)(hap_c + (size_t)i3 * 32);
        b0 += (bf2f_lo(u0) + bf2f_lo(u1)) + (bf2f_lo(u2) + bf2f_lo(u3));
        b1 += (bf2f_hi(u0) + bf2f_hi(u1)) + (bf2f_hi(u2) + bf2f_hi(u3));
    }
    for (; j < e2; ++j) {
        unsigned u0 = *(const unsigned*)(hap_c + (size_t)ntl(csr_ap + j) * 32);
        b0 += bf2f_lo(u0); b1 += bf2f_hi(u0);
    }
    float ipp = 1.0f / fmaxf((float)k1, 1.0f);
    float iap = 1.0f / fmaxf((float)k2, 1.0f);
    float p0 = fmaxf(root[(size_t)n * 32 + 2 * c]     + a0 * ipp + b0 * iap, 0.f);
    float p1 = fmaxf(root[(size_t)n * 32 + 2 * c + 1] + a1 * ipp + b1 * iap, 0.f);
    float d0 = p0 * v0[2 * c] + p1 * v0[2 * c + 1];
    float d1 = p0 * v1[2 * c] + p1 * v1[2 * c + 1];
#pragma unroll
    for (int off = 1; off < 16; off <<= 1) {
        d0 += __shfl_xor(d0, off);
        d1 += __shfl_xor(d1, off);
    }
    if (c == 0) { s_pp[n] = d0; out[n] = d1 + c2s; }
}

__global__ __launch_bounds__(256, 8)
void pull_author(const ushort_t* __restrict__ h_pa, const float* __restrict__ root,
                 const int* __restrict__ csr_pa, const int* __restrict__ rs_pa,
                 const int* __restrict__ cnt_pa,
                 const float* __restrict__ vv, float* __restrict__ s_ap, int N)
{
    __shared__ float v0[32];
    if (threadIdx.x < 32) v0[threadIdx.x] = vv[96 + threadIdx.x];
    __syncthreads();
    int n = blockIdx.x * 16 + (threadIdx.x >> 4);
    if (n >= N) return;
    int c = threadIdx.x & 15;
    const ushort_t* hpa_c = h_pa + 2 * c;
    int s1 = rs_pa[n], k1 = cnt_pa[n], e1 = s1 + k1;
    float a0 = 0.f, a1 = 0.f;
    int j = s1;
    for (; j + 4 <= e1; j += 4) {
        int i0 = ntl(csr_pa + j), i1 = ntl(csr_pa + j + 1);
        int i2 = ntl(csr_pa + j + 2), i3 = ntl(csr_pa + j + 3);
        unsigned u0 = *(const unsigned*)(hpa_c + (size_t)i0 * 32);
        unsigned u1 = *(const unsigned*)(hpa_c + (size_t)i1 * 32);
        unsigned u2 = *(const unsigned*)(hpa_c + (size_t)i2 * 32);
        unsigned u3 = *(const unsigned*)(hpa_c + (size_t)i3 * 32);
        a0 += (bf2f_lo(u0) + bf2f_lo(u1)) + (bf2f_lo(u2) + bf2f_lo(u3));
        a1 += (bf2f_hi(u0) + bf2f_hi(u1)) + (bf2f_hi(u2) + bf2f_hi(u3));
    }
    for (; j < e1; ++j) {
        unsigned u0 = *(const unsigned*)(hpa_c + (size_t)ntl(csr_pa + j) * 32);
        a0 += bf2f_lo(u0); a1 += bf2f_hi(u0);
    }
    float ip = 1.0f / fmaxf((float)k1, 1.0f);
    float p0 = fmaxf(root[(size_t)n * 32 + 2 * c]     + a0 * ip, 0.f);
    float p1 = fmaxf(root[(size_t)n * 32 + 2 * c + 1] + a1 * ip, 0.f);
    float d0 = p0 * v0[2 * c] + p1 * v0[2 * c + 1];
#pragma unroll
    for (int off = 1; off < 16; off <<= 1) d0 += __shfl_xor(d0, off);
    if (c == 0) s_ap[n] = d0;
}

// layer-2 scalar pull, 4 lanes/node.
__global__ __launch_bounds__(256, 8)
void pull2(const float* __restrict__ s_pp, const float* __restrict__ s_ap,
           const int* __restrict__ csr_pp, const int* __restrict__ rs_pp,
           const int* __restrict__ cnt_pp,
           const int* __restrict__ csr_ap, const int* __restrict__ rs_ap,
           const int* __restrict__ cnt_ap,
           float* __restrict__ out, int N)
{
    int g = (blockIdx.x * blockDim.x + threadIdx.x) >> 2;
    int c = threadIdx.x & 3;
    if (g >= N) return;
    int s1 = rs_pp[g], k1 = cnt_pp[g], e1 = s1 + k1;
    float t = 0.f;
    for (int j = s1 + c; j < e1; j += 4) t += s_pp[ntl(csr_pp + j)];
    int s2 = rs_ap[g], k2 = cnt_ap[g], e2 = s2 + k2;
    float u = 0.f;
    for (int j = s2 + c; j < e2; j += 4) u += s_ap[ntl(csr_ap + j)];
    t += __shfl_xor(t, 1); t += __shfl_xor(t, 2);
    u += __shfl_xor(u, 1); u += __shfl_xor(u, 2);
    if (c == 0) {
        out[g] += t / fmaxf((float)k1, 1.f) + u / fmaxf((float)k2, 1.f);
    }
}

extern "C" void kernel_launch(void* const* d_in, const int* in_sizes, int n_in,
                              void* d_out, int out_size, void* d_ws, size_t ws_size,
                              hipStream_t stream)
{
    const float* x_paper  = (const float*)d_in[0];
    const float* x_author = (const float*)d_in[1];
    const int* src_pp = (const int*)d_in[2];
    const int* dst_pp = (const int*)d_in[3];
    const int* src_ap = (const int*)d_in[4];
    const int* dst_ap = (const int*)d_in[5];
    const int* src_pa = (const int*)d_in[6];
    const int* dst_pa = (const int*)d_in[7];
    const float* Wl1_pp = (const float*)d_in[8];
    const float* bl1_pp = (const float*)d_in[9];
    const float* Wr1_pp = (const float*)d_in[10];
    const float* Wl1_ap = (const float*)d_in[11];
    const float* bl1_ap = (const float*)d_in[12];
    const float* Wr1_ap = (const float*)d_in[13];
    const float* Wl1_pa = (const float*)d_in[14];
    const float* bl1_pa = (const float*)d_in[15];
    const float* Wr1_pa = (const float*)d_in[16];
    const float* Wl2_pp = (const float*)d_in[17];
    const float* bl2_pp = (const float*)d_in[18];
    const float* Wr2_pp = (const float*)d_in[19];
    const float* Wl2_ap = (const float*)d_in[20];
    const float* bl2_ap = (const float*)d_in[21];
    const float* Wr2_ap = (const float*)d_in[22];
    const float* W_lin  = (const float*)d_in[23];
    const float* b_lin  = (const float*)d_in[24];

    const int NP = in_sizes[0] / 64;
    const int NA = in_sizes[1] / 64;
    const int E_PP = in_sizes[2];
    const int E_AP = in_sizes[4];
    const int E_PA = in_sizes[6];

    const int nw_pp = (NP + PWIN - 1) >> PWBITS;   // 196
    const int nw_ap = nw_pp;                       // 196
    const int nw_pa = (NA + PWIN - 1) >> PWBITS;   // 98
    const int cap_pp = E_PP / nw_pp + CAPPAD;
    const int cap_ap = E_AP / nw_ap + CAPPAD;
    const int cap_pa = E_PA / nw_pa + CAPPAD;

    // ---- workspace ----
    char* wp = (char*)d_ws;
    int* wcur = (int*)wp;             wp += 768 * 4;   // 3 x 256, zeroed
    unsigned* bk_pp = (unsigned*)wp;  wp += (size_t)nw_pp * cap_pp * 4;
    unsigned* bk_ap = (unsigned*)wp;  wp += (size_t)nw_ap * cap_ap * 4;
    unsigned* bk_pa = (unsigned*)wp;  wp += (size_t)nw_pa * cap_pa * 4;
    int* csr_pp = (int*)wp;           wp += (size_t)nw_pp * cap_pp * 4;
    int* csr_ap = (int*)wp;           wp += (size_t)nw_ap * cap_ap * 4;
    int* csr_pa = (int*)wp;           wp += (size_t)nw_pa * cap_pa * 4;
    int* cnt    = (int*)wp;           wp += (size_t)(2 * NP + NA) * 4;
    int* rs     = (int*)wp;           wp += (size_t)(2 * NP + NA) * 4;
    ushort_t* h_pp = (ushort_t*)wp;   wp += (size_t)NP * 32 * 2;
    ushort_t* h_pa = (ushort_t*)wp;   wp += (size_t)NP * 32 * 2;
    ushort_t* h_ap = (ushort_t*)wp;   wp += (size_t)NA * 32 * 2;
    float* root_a = (float*)wp;       wp += (size_t)NA * 32 * 4;
    float* s_pp   = (float*)wp;       wp += (size_t)NP * 4;
    float* s_ap   = (float*)wp;       wp += (size_t)NA * 4;
    float* Wcomb_p = (float*)wp;      wp += 64 * 96 * 4;
    float* Wcomb_a = (float*)wp;      wp += 64 * 64 * 4;
    ushort_t* Wfrag_p = (ushort_t*)wp; wp += 12 * 64 * 8 * 2;
    ushort_t* Wfrag_a = (ushort_t*)wp; wp += 8 * 64 * 8 * 2;
    float* bias_p = (float*)wp;       wp += 32 * 4;
    float* bias_a = (float*)wp;       wp += 32 * 4;
    float* vv     = (float*)wp;       wp += 128 * 4;
    // root_p overlays the (dead after fill_win3) bucket region bk_pp..bk_ap
    float* root_p = (float*)bk_pp;    // NP*32*4 = 25.6MB <= bk_pp+bk_ap ~25.6MB

    int* cnt_pp = cnt,  * cnt_ap = cnt + NP,  * cnt_pa = cnt + 2 * NP;
    int* rs_pp  = rs,   * rs_ap  = rs + NP,   * rs_pa  = rs + 2 * NP;

    float* out = (float*)d_out;

    // zero the window cursors only
    hipMemsetAsync(wcur, 0, 768 * sizeof(int), stream);

    prep_weights<<<1, 256, 0, stream>>>(
        Wl1_pp, Wr1_pp, Wl1_ap, Wr1_ap, Wl1_pa, Wr1_pa,
        bl1_pp, bl1_ap, bl1_pa,
        Wl2_pp, bl2_pp, Wr2_pp, Wl2_ap, bl2_ap, Wr2_ap,
        W_lin, b_lin, Wcomb_p, Wcomb_a, Wfrag_p, Wfrag_a, bias_p, bias_a, vv);

    int nb_total = (E_PP + PCHUNK - 1) / PCHUNK + (E_AP + PCHUNK - 1) / PCHUNK
                 + (E_PA + PCHUNK - 1) / PCHUNK;
    partition3<<<nb_total, 256, 0, stream>>>(
        src_pp, dst_pp, E_PP, bk_pp, cap_pp, nw_pp, wcur + 0,
        src_ap, dst_ap, E_AP, bk_ap, cap_ap, nw_ap, wcur + 256,
        src_pa, dst_pa, E_PA, bk_pa, cap_pa, nw_pa, wcur + 512);

    fill_win3<<<nw_pp + nw_ap + nw_pa, 256, 0, stream>>>(
        bk_pp, wcur + 0,   cap_pp, csr_pp, cnt_pp, rs_pp, NP, nw_pp,
        bk_ap, wcur + 256, cap_ap, csr_ap, cnt_ap, rs_ap, NP, nw_ap,
        bk_pa, wcur + 512, cap_pa, csr_pa, cnt_pa, rs_pa, NA, nw_pa);

    proj_paper_mfma<<<(NP + 63) / 64, 256, 0, stream>>>(
        x_paper, Wfrag_p, bias_p, h_pp, h_pa, root_p, NP);
    proj_author_mfma<<<(NA + 63) / 64, 256, 0, stream>>>(
        x_author, Wfrag_a, bias_a, h_ap, root_a, NA);

    pull_paper<<<(NP + 15) / 16, 256, 0, stream>>>(
        h_pp, h_ap, root_p, csr_pp, rs_pp, cnt_pp, csr_ap, rs_ap, cnt_ap,
        vv, s_pp, out, NP);
    pull_author<<<(NA + 15) / 16, 256, 0, stream>>>(
        h_pa, root_a, csr_pa, rs_pa, cnt_pa, vv, s_ap, NA);

    pull2<<<((size_t)NP * 4 + 255) / 256, 256, 0, stream>>>(
        s_pp, s_ap, csr_pp, rs_pp, cnt_pp, csr_ap, rs_ap, cnt_ap, out, NP);
}

// Round 13
// 417.851 us; speedup vs baseline: 2.4539x; 1.0742x over previous
//
#include <hip/hip_runtime.h>

// ---------------------------------------------------------------------------
// HeteroSAGE: CSR pull; CSR built with ZERO per-edge global atomics.
//   partition3 -> fill_win3 (round-11, unchanged)
//   proj via MFMA 16x16x32 bf16 (round-12, unchanged)
//   pull: 4 lanes/node, dwordx4 gathers (4x rows in flight per wave),
//   fuses mean + root + relu + layer-2 dots -> pull2 scalar layer-2.
// ---------------------------------------------------------------------------

typedef unsigned short ushort_t;
typedef __attribute__((ext_vector_type(8))) short bf16x8;
typedef __attribute__((ext_vector_type(4))) float f32x4;

#define PWBITS 10
#define PWIN   (1 << PWBITS)     // 1024 dsts per window
#define PCHUNK 8192              // edges per partition chunk
#define CAPPAD 4096              // bucket slack

__device__ inline ushort_t f2bf(float f) {
    unsigned u = __float_as_uint(f);
    unsigned r = (u + 0x7FFFu + ((u >> 16) & 1u)) >> 16;
    return (ushort_t)r;
}
__device__ inline float bf2f_lo(unsigned u) { return __uint_as_float(u << 16); }
__device__ inline float bf2f_hi(unsigned u) { return __uint_as_float(u & 0xFFFF0000u); }
__device__ inline int ntl(const int* p) { return __builtin_nontemporal_load(p); }
__device__ inline unsigned ntlu(const unsigned* p) { return __builtin_nontemporal_load(p); }

__global__ void prep_weights(
    const float* __restrict__ Wl1_pp, const float* __restrict__ Wr1_pp,
    const float* __restrict__ Wl1_ap, const float* __restrict__ Wr1_ap,
    const float* __restrict__ Wl1_pa, const float* __restrict__ Wr1_pa,
    const float* __restrict__ bl1_pp, const float* __restrict__ bl1_ap,
    const float* __restrict__ bl1_pa,
    const float* __restrict__ Wl2_pp, const float* __restrict__ bl2_pp,
    const float* __restrict__ Wr2_pp,
    const float* __restrict__ Wl2_ap, const float* __restrict__ bl2_ap,
    const float* __restrict__ Wr2_ap,
    const float* __restrict__ W_lin, const float* __restrict__ b_lin,
    float* __restrict__ Wcomb_p,   // 64 x 96: [Wl1_pp | Wl1_pa | Wr1_pp+Wr1_ap]
    float* __restrict__ Wcomb_a,   // 64 x 64: [Wl1_ap | Wr1_pa]
    ushort_t* __restrict__ Wfrag_p, // 12 frags x 64 lanes x 8 bf16 (B-frag layout)
    ushort_t* __restrict__ Wfrag_a, // 8 frags x 64 lanes x 8
    float* __restrict__ bias_p,    // 32
    float* __restrict__ bias_a,    // 32
    float* __restrict__ vv)        // [0:32) v_pp [32:64) v_r [64] c2 [96:128) v_ap
{
    int t = threadIdx.x;
    for (int idx = t; idx < 64 * 96; idx += 256) {
        int i = idx / 96, j = idx % 96;
        float v;
        if (j < 32)       v = Wl1_pp[i * 32 + j];
        else if (j < 64)  v = Wl1_pa[i * 32 + (j - 32)];
        else              v = Wr1_pp[i * 32 + (j - 64)] + Wr1_ap[i * 32 + (j - 64)];
        Wcomb_p[idx] = v;
    }
    for (int idx = t; idx < 64 * 64; idx += 256) {
        int i = idx / 64, j = idx % 64;
        Wcomb_a[idx] = (j < 32) ? Wl1_ap[i * 32 + j] : Wr1_pa[i * 32 + (j - 32)];
    }
    if (t < 32) {
        bias_p[t] = bl1_pp[t] + bl1_ap[t];
        bias_a[t] = bl1_pa[t];
        float vpp = 0.f, vr = 0.f, vap = 0.f;
        for (int j = 0; j < 32; ++j) {
            float wl = W_lin[j];
            vpp += Wl2_pp[t * 32 + j] * wl;
            vr  += (Wr2_pp[t * 32 + j] + Wr2_ap[t * 32 + j]) * wl;
            vap += Wl2_ap[t * 32 + j] * wl;
        }
        vv[t] = vpp; vv[32 + t] = vr; vv[96 + t] = vap;
    }
    if (t == 0) {
        float c = b_lin[0];
        for (int j = 0; j < 32; ++j) c += (bl2_pp[j] + bl2_ap[j]) * W_lin[j];
        vv[64] = c;
    }
    __syncthreads();
    // B-fragment packing for mfma_f32_16x16x32_bf16:
    // frag f = nt*2+kh; lane l, elem j -> B[k][n] with
    // k = kh*32 + 8*(l>>4) + j, n = nt*16 + (l&15).
    for (int idx = t; idx < 12 * 64 * 8; idx += 256) {
        int f = idx >> 9, l = (idx >> 3) & 63, j = idx & 7;
        int nt = f >> 1, kh = f & 1;
        int k = kh * 32 + 8 * (l >> 4) + j;
        int n = nt * 16 + (l & 15);
        Wfrag_p[idx] = f2bf(Wcomb_p[k * 96 + n]);
    }
    for (int idx = t; idx < 8 * 64 * 8; idx += 256) {
        int f = idx >> 9, l = (idx >> 3) & 63, j = idx & 7;
        int nt = f >> 1, kh = f & 1;
        int k = kh * 32 + 8 * (l >> 4) + j;
        int n = nt * 16 + (l & 15);
        Wfrag_a[idx] = f2bf(Wcomb_a[k * 64 + n]);
    }
}

// one launch, all 3 relations: group edges by dst-window via LDS counts +
// claimed contiguous bucket runs; packed coalesced writes.
__global__ __launch_bounds__(256)
void partition3(
    const int* __restrict__ src0, const int* __restrict__ dst0, int E0,
    unsigned* __restrict__ bk0, int cap0, int nw0, int* __restrict__ wc0,
    const int* __restrict__ src1, const int* __restrict__ dst1, int E1,
    unsigned* __restrict__ bk1, int cap1, int nw1, int* __restrict__ wc1,
    const int* __restrict__ src2, const int* __restrict__ dst2, int E2,
    unsigned* __restrict__ bk2, int cap2, int nw2, int* __restrict__ wc2)
{
    __shared__ int lcnt[256];
    __shared__ int lbase[256];
    int nb0 = (E0 + PCHUNK - 1) / PCHUNK;
    int nb1 = (E1 + PCHUNK - 1) / PCHUNK;
    int b = blockIdx.x;
    const int* src; const int* dst; int E; unsigned* bk; int cap; int nw; int* wc; int chunk;
    if (b < nb0)            { src = src0; dst = dst0; E = E0; bk = bk0; cap = cap0; nw = nw0; wc = wc0; chunk = b; }
    else if (b < nb0 + nb1) { src = src1; dst = dst1; E = E1; bk = bk1; cap = cap1; nw = nw1; wc = wc1; chunk = b - nb0; }
    else                    { src = src2; dst = dst2; E = E2; bk = bk2; cap = cap2; nw = nw2; wc = wc2; chunk = b - nb0 - nb1; }
    int e0 = chunk * PCHUNK;
    int e1 = e0 + PCHUNK; if (e1 > E) e1 = E;
    for (int i = threadIdx.x; i < nw; i += 256) lcnt[i] = 0;
    __syncthreads();
    for (int e = e0 + threadIdx.x; e < e1; e += 256)
        atomicAdd(&lcnt[((unsigned)ntl(dst + e)) >> PWBITS], 1);
    __syncthreads();
    for (int i = threadIdx.x; i < nw; i += 256) {
        int c = lcnt[i];
        lbase[i] = (c > 0) ? atomicAdd(&wc[i], c) : 0;
        lcnt[i] = 0;
    }
    __syncthreads();
    for (int e = e0 + threadIdx.x; e < e1; e += 256) {
        int d = ntl(dst + e);
        int w = ((unsigned)d) >> PWBITS;
        int off = lbase[w] + atomicAdd(&lcnt[w], 1);
        if (off < cap)
            bk[(size_t)w * cap + off] =
                (((unsigned)(d & (PWIN - 1))) << 18) | (unsigned)ntl(src + e);
    }
}

// one launch, one 256-thread block per window across all 3 relations.
__global__ __launch_bounds__(256)
void fill_win3(
    const unsigned* __restrict__ bk0, const int* __restrict__ wc0, int cap0,
    int* __restrict__ csr0, int* __restrict__ cnt0, int* __restrict__ rs0, int N0, int nw0,
    const unsigned* __restrict__ bk1, const int* __restrict__ wc1, int cap1,
    int* __restrict__ csr1, int* __restrict__ cnt1, int* __restrict__ rs1, int N1, int nw1,
    const unsigned* __restrict__ bk2, const int* __restrict__ wc2, int cap2,
    int* __restrict__ csr2, int* __restrict__ cnt2, int* __restrict__ rs2, int N2, int nw2)
{
    __shared__ int lc[PWIN];
    __shared__ int wsum[4], wpre[4];
    int b = blockIdx.x;
    const unsigned* bk; const int* wc; int cap; int* csr; int* cnt; int* rs; int N; int w;
    if (b < nw0)            { bk = bk0; wc = wc0; cap = cap0; csr = csr0; cnt = cnt0; rs = rs0; N = N0; w = b; }
    else if (b < nw0 + nw1) { bk = bk1; wc = wc1; cap = cap1; csr = csr1; cnt = cnt1; rs = rs1; N = N1; w = b - nw0; }
    else                    { bk = bk2; wc = wc2; cap = cap2; csr = csr2; cnt = cnt2; rs = rs2; N = N2; w = b - nw0 - nw1; }
    int d0 = w << PWBITS;
    int sz = wc[w]; if (sz > cap) sz = cap;
    const unsigned* bkt = bk + (size_t)w * cap;
    for (int i = threadIdx.x; i < PWIN; i += 256) lc[i] = 0;
    __syncthreads();
    for (int i = threadIdx.x; i < sz; i += 256)
        atomicAdd(&lc[ntlu(bkt + i) >> 18], 1);
    __syncthreads();
    for (int i = threadIdx.x; i < PWIN; i += 256) {
        int d = d0 + i;
        if (d < N) cnt[d] = lc[i];
    }
    __syncthreads();
    int bi = threadIdx.x * 4;
    int v[4]; int ts = 0;
#pragma unroll
    for (int k = 0; k < 4; ++k) { v[k] = lc[bi + k]; ts += v[k]; }
    int lane = threadIdx.x & 63;
    int wid = threadIdx.x >> 6;
    int incl = ts;
#pragma unroll
    for (int off = 1; off < 64; off <<= 1) {
        int o = __shfl_up(incl, off);
        if (lane >= off) incl += o;
    }
    if (lane == 63) wsum[wid] = incl;
    __syncthreads();
    if (threadIdx.x == 0) {
        int r = 0;
        for (int i = 0; i < 4; ++i) { wpre[i] = r; r += wsum[i]; }
    }
    __syncthreads();
    int run = w * cap + wpre[wid] + (incl - ts);
#pragma unroll
    for (int k = 0; k < 4; ++k) {
        int d = d0 + bi + k;
        lc[bi + k] = run;
        if (d < N) rs[d] = run;
        run += v[k];
    }
    __syncthreads();
    for (int i = threadIdx.x; i < sz; i += 256) {
        unsigned u = ntlu(bkt + i);
        int pos = atomicAdd(&lc[u >> 18], 1);
        csr[pos] = (int)(u & 0x3FFFFu);
    }
}

__device__ inline bf16x8 cvt8(const float* p) {
    float4 a = *(const float4*)p;
    float4 b = *(const float4*)(p + 4);
    bf16x8 r;
    r[0] = (short)f2bf(a.x); r[1] = (short)f2bf(a.y);
    r[2] = (short)f2bf(a.z); r[3] = (short)f2bf(a.w);
    r[4] = (short)f2bf(b.x); r[5] = (short)f2bf(b.y);
    r[6] = (short)f2bf(b.z); r[7] = (short)f2bf(b.w);
    return r;
}

// MFMA projection, paper: 4 waves x 16 nodes = 64 nodes/block; 6 N-tiles.
__global__ __launch_bounds__(256)
void proj_paper_mfma(const float* __restrict__ x, const ushort_t* __restrict__ Wfrag,
                     const float* __restrict__ bias,
                     ushort_t* __restrict__ h_pp, ushort_t* __restrict__ h_pa,
                     float* __restrict__ root_p, int N)
{
    int wave = threadIdx.x >> 6, lane = threadIdx.x & 63;
    int mbase = blockIdx.x * 64 + wave * 16;
    int row = lane & 15, grp = lane >> 4;
    int nA = mbase + row; if (nA > N - 1) nA = N - 1;
    const float* xr = x + (size_t)nA * 64 + grp * 8;
    bf16x8 a0 = cvt8(xr);        // k = grp*8 + j
    bf16x8 a1 = cvt8(xr + 32);   // k = 32 + grp*8 + j
    f32x4 acc0 = {0.f, 0.f, 0.f, 0.f}, acc1 = acc0, acc2 = acc0, acc3 = acc0;
    float bp0 = bias[row];        // nt=4: col=row
    float bp1 = bias[16 + row];   // nt=5
    f32x4 acc4 = {bp0, bp0, bp0, bp0};
    f32x4 acc5 = {bp1, bp1, bp1, bp1};
    const bf16x8* wf = (const bf16x8*)(Wfrag) + lane;  // frag f at wf[f*64]
    acc0 = __builtin_amdgcn_mfma_f32_16x16x32_bf16(a0, wf[0 * 64], acc0, 0, 0, 0);
    acc0 = __builtin_amdgcn_mfma_f32_16x16x32_bf16(a1, wf[1 * 64], acc0, 0, 0, 0);
    acc1 = __builtin_amdgcn_mfma_f32_16x16x32_bf16(a0, wf[2 * 64], acc1, 0, 0, 0);
    acc1 = __builtin_amdgcn_mfma_f32_16x16x32_bf16(a1, wf[3 * 64], acc1, 0, 0, 0);
    acc2 = __builtin_amdgcn_mfma_f32_16x16x32_bf16(a0, wf[4 * 64], acc2, 0, 0, 0);
    acc2 = __builtin_amdgcn_mfma_f32_16x16x32_bf16(a1, wf[5 * 64], acc2, 0, 0, 0);
    acc3 = __builtin_amdgcn_mfma_f32_16x16x32_bf16(a0, wf[6 * 64], acc3, 0, 0, 0);
    acc3 = __builtin_amdgcn_mfma_f32_16x16x32_bf16(a1, wf[7 * 64], acc3, 0, 0, 0);
    acc4 = __builtin_amdgcn_mfma_f32_16x16x32_bf16(a0, wf[8 * 64], acc4, 0, 0, 0);
    acc4 = __builtin_amdgcn_mfma_f32_16x16x32_bf16(a1, wf[9 * 64], acc4, 0, 0, 0);
    acc5 = __builtin_amdgcn_mfma_f32_16x16x32_bf16(a0, wf[10 * 64], acc5, 0, 0, 0);
    acc5 = __builtin_amdgcn_mfma_f32_16x16x32_bf16(a1, wf[11 * 64], acc5, 0, 0, 0);
    int col = row;
    int node0 = mbase + grp * 4;
#pragma unroll
    for (int reg = 0; reg < 4; ++reg) {
        int nd = node0 + reg;
        if (nd < N) {
            size_t b32 = (size_t)nd * 32;
            h_pp[b32 + col]        = f2bf(acc0[reg]);
            h_pp[b32 + 16 + col]   = f2bf(acc1[reg]);
            h_pa[b32 + col]        = f2bf(acc2[reg]);
            h_pa[b32 + 16 + col]   = f2bf(acc3[reg]);
            root_p[b32 + col]      = acc4[reg];
            root_p[b32 + 16 + col] = acc5[reg];
        }
    }
}

// MFMA projection, author: 4 N-tiles.
__global__ __launch_bounds__(256)
void proj_author_mfma(const float* __restrict__ x, const ushort_t* __restrict__ Wfrag,
                      const float* __restrict__ bias,
                      ushort_t* __restrict__ h_ap, float* __restrict__ root_a, int N)
{
    int wave = threadIdx.x >> 6, lane = threadIdx.x & 63;
    int mbase = blockIdx.x * 64 + wave * 16;
    int row = lane & 15, grp = lane >> 4;
    int nA = mbase + row; if (nA > N - 1) nA = N - 1;
    const float* xr = x + (size_t)nA * 64 + grp * 8;
    bf16x8 a0 = cvt8(xr);
    bf16x8 a1 = cvt8(xr + 32);
    f32x4 acc0 = {0.f, 0.f, 0.f, 0.f}, acc1 = acc0;
    float bp0 = bias[row];
    float bp1 = bias[16 + row];
    f32x4 acc2 = {bp0, bp0, bp0, bp0};
    f32x4 acc3 = {bp1, bp1, bp1, bp1};
    const bf16x8* wf = (const bf16x8*)(Wfrag) + lane;
    acc0 = __builtin_amdgcn_mfma_f32_16x16x32_bf16(a0, wf[0 * 64], acc0, 0, 0, 0);
    acc0 = __builtin_amdgcn_mfma_f32_16x16x32_bf16(a1, wf[1 * 64], acc0, 0, 0, 0);
    acc1 = __builtin_amdgcn_mfma_f32_16x16x32_bf16(a0, wf[2 * 64], acc1, 0, 0, 0);
    acc1 = __builtin_amdgcn_mfma_f32_16x16x32_bf16(a1, wf[3 * 64], acc1, 0, 0, 0);
    acc2 = __builtin_amdgcn_mfma_f32_16x16x32_bf16(a0, wf[4 * 64], acc2, 0, 0, 0);
    acc2 = __builtin_amdgcn_mfma_f32_16x16x32_bf16(a1, wf[5 * 64], acc2, 0, 0, 0);
    acc3 = __builtin_amdgcn_mfma_f32_16x16x32_bf16(a0, wf[6 * 64], acc3, 0, 0, 0);
    acc3 = __builtin_amdgcn_mfma_f32_16x16x32_bf16(a1, wf[7 * 64], acc3, 0, 0, 0);
    int col = row;
    int node0 = mbase + grp * 4;
#pragma unroll
    for (int reg = 0; reg < 4; ++reg) {
        int nd = node0 + reg;
        if (nd < N) {
            size_t b32 = (size_t)nd * 32;
            h_ap[b32 + col]        = f2bf(acc0[reg]);
            h_ap[b32 + 16 + col]   = f2bf(acc1[reg]);
            root_a[b32 + col]      = acc2[reg];
            root_a[b32 + 16 + col] = acc3[reg];
        }
    }
}

#define ACC8(A, U) \
    A[0] += bf2f_lo((U).x); A[1] += bf2f_hi((U).x); \
    A[2] += bf2f_lo((U).y); A[3] += bf2f_hi((U).y); \
    A[4] += bf2f_lo((U).z); A[5] += bf2f_hi((U).z); \
    A[6] += bf2f_lo((U).w); A[7] += bf2f_hi((U).w);

// 4 lanes/node, dwordx4 gathers: 16 rows in flight per wave.
// Fuses mean + root + relu + layer-2 dot products.
__global__ __launch_bounds__(256, 8)
void pull_paper(const ushort_t* __restrict__ h_pp, const ushort_t* __restrict__ h_ap,
                const float* __restrict__ root,
                const int* __restrict__ csr_pp, const int* __restrict__ rs_pp,
                const int* __restrict__ cnt_pp,
                const int* __restrict__ csr_ap, const int* __restrict__ rs_ap,
                const int* __restrict__ cnt_ap,
                const float* __restrict__ vv,
                float* __restrict__ s_pp, float* __restrict__ out, int N)
{
    __shared__ float v0[32], v1[32];
    __shared__ float c2s;
    if (threadIdx.x < 32) { v0[threadIdx.x] = vv[threadIdx.x]; v1[threadIdx.x] = vv[32 + threadIdx.x]; }
    if (threadIdx.x == 0) c2s = vv[64];
    __syncthreads();
    int n = blockIdx.x * 64 + (threadIdx.x >> 2);
    if (n >= N) return;
    int c = threadIdx.x & 3;   // cols 8c..8c+7
    float a[8];
#pragma unroll
    for (int k = 0; k < 8; ++k) a[k] = 0.f;
    int s1 = rs_pp[n], k1 = cnt_pp[n], e1 = s1 + k1;
    int j = s1;
    for (; j + 4 <= e1; j += 4) {
        int i0 = ntl(csr_pp + j), i1 = ntl(csr_pp + j + 1);
        int i2 = ntl(csr_pp + j + 2), i3 = ntl(csr_pp + j + 3);
        uint4 u0 = ((const uint4*)(h_pp + (size_t)i0 * 32))[c];
        uint4 u1 = ((const uint4*)(h_pp + (size_t)i1 * 32))[c];
        uint4 u2 = ((const uint4*)(h_pp + (size_t)i2 * 32))[c];
        uint4 u3 = ((const uint4*)(h_pp + (size_t)i3 * 32))[c];
        ACC8(a, u0) ACC8(a, u1) ACC8(a, u2) ACC8(a, u3)
    }
    for (; j < e1; ++j) {
        uint4 u0 = ((const uint4*)(h_pp + (size_t)ntl(csr_pp + j) * 32))[c];
        ACC8(a, u0)
    }
    float b[8];
#pragma unroll
    for (int k = 0; k < 8; ++k) b[k] = 0.f;
    int s2 = rs_ap[n], k2 = cnt_ap[n], e2 = s2 + k2;
    j = s2;
    for (; j + 4 <= e2; j += 4) {
        int i0 = ntl(csr_ap + j), i1 = ntl(csr_ap + j + 1);
        int i2 = ntl(csr_ap + j + 2), i3 = ntl(csr_ap + j + 3);
        uint4 u0 = ((const uint4*)(h_ap + (size_t)i0 * 32))[c];
        uint4 u1 = ((const uint4*)(h_ap + (size_t)i1 * 32))[c];
        uint4 u2 = ((const uint4*)(h_ap + (size_t)i2 * 32))[c];
        uint4 u3 = ((const uint4*)(h_ap + (size_t)i3 * 32))[c];
        ACC8(b, u0) ACC8(b, u1) ACC8(b, u2) ACC8(b, u3)
    }
    for (; j < e2; ++j) {
        uint4 u0 = ((const uint4*)(h_ap + (size_t)ntl(csr_ap + j) * 32))[c];
        ACC8(b, u0)
    }
    float ipp = 1.0f / fmaxf((float)k1, 1.0f);
    float iap = 1.0f / fmaxf((float)k2, 1.0f);
    const float* rt = root + (size_t)n * 32 + 8 * c;
    float d0 = 0.f, d1 = 0.f;
#pragma unroll
    for (int k = 0; k < 8; ++k) {
        float p = fmaxf(rt[k] + a[k] * ipp + b[k] * iap, 0.f);
        d0 += p * v0[8 * c + k];
        d1 += p * v1[8 * c + k];
    }
    d0 += __shfl_xor(d0, 1); d0 += __shfl_xor(d0, 2);
    d1 += __shfl_xor(d1, 1); d1 += __shfl_xor(d1, 2);
    if (c == 0) { s_pp[n] = d0; out[n] = d1 + c2s; }
}

__global__ __launch_bounds__(256, 8)
void pull_author(const ushort_t* __restrict__ h_pa, const float* __restrict__ root,
                 const int* __restrict__ csr_pa, const int* __restrict__ rs_pa,
                 const int* __restrict__ cnt_pa,
                 const float* __restrict__ vv, float* __restrict__ s_ap, int N)
{
    __shared__ float v0[32];
    if (threadIdx.x < 32) v0[threadIdx.x] = vv[96 + threadIdx.x];
    __syncthreads();
    int n = blockIdx.x * 64 + (threadIdx.x >> 2);
    if (n >= N) return;
    int c = threadIdx.x & 3;
    float a[8];
#pragma unroll
    for (int k = 0; k < 8; ++k) a[k] = 0.f;
    int s1 = rs_pa[n], k1 = cnt_pa[n], e1 = s1 + k1;
    int j = s1;
    for (; j + 4 <= e1; j += 4) {
        int i0 = ntl(csr_pa + j), i1 = ntl(csr_pa + j + 1);
        int i2 = ntl(csr_pa + j + 2), i3 = ntl(csr_pa + j + 3);
        uint4 u0 = ((const uint4*)(h_pa + (size_t)i0 * 32))[c];
        uint4 u1 = ((const uint4*)(h_pa + (size_t)i1 * 32))[c];
        uint4 u2 = ((const uint4*)(h_pa + (size_t)i2 * 32))[c];
        uint4 u3 = ((const uint4*)(h_pa + (size_t)i3 * 32))[c];
        ACC8(a, u0) ACC8(a, u1) ACC8(a, u2) ACC8(a, u3)
    }
    for (; j < e1; ++j) {
        uint4 u0 = ((const uint4*)(h_pa + (size_t)ntl(csr_pa + j) * 32))[c];
        ACC8(a, u0)
    }
    float ip = 1.0f / fmaxf((float)k1, 1.0f);
    const float* rt = root + (size_t)n * 32 + 8 * c;
    float d0 = 0.f;
#pragma unroll
    for (int k = 0; k < 8; ++k) {
        float p = fmaxf(rt[k] + a[k] * ip, 0.f);
        d0 += p * v0[8 * c + k];
    }
    d0 += __shfl_xor(d0, 1); d0 += __shfl_xor(d0, 2);
    if (c == 0) s_ap[n] = d0;
}

// layer-2 scalar pull, 4 lanes/node.
__global__ __launch_bounds__(256, 8)
void pull2(const float* __restrict__ s_pp, const float* __restrict__ s_ap,
           const int* __restrict__ csr_pp, const int* __restrict__ rs_pp,
           const int* __restrict__ cnt_pp,
           const int* __restrict__ csr_ap, const int* __restrict__ rs_ap,
           const int* __restrict__ cnt_ap,
           float* __restrict__ out, int N)
{
    int g = (blockIdx.x * blockDim.x + threadIdx.x) >> 2;
    int c = threadIdx.x & 3;
    if (g >= N) return;
    int s1 = rs_pp[g], k1 = cnt_pp[g], e1 = s1 + k1;
    float t = 0.f;
    for (int j = s1 + c; j < e1; j += 4) t += s_pp[ntl(csr_pp + j)];
    int s2 = rs_ap[g], k2 = cnt_ap[g], e2 = s2 + k2;
    float u = 0.f;
    for (int j = s2 + c; j < e2; j += 4) u += s_ap[ntl(csr_ap + j)];
    t += __shfl_xor(t, 1); t += __shfl_xor(t, 2);
    u += __shfl_xor(u, 1); u += __shfl_xor(u, 2);
    if (c == 0) {
        out[g] += t / fmaxf((float)k1, 1.f) + u / fmaxf((float)k2, 1.f);
    }
}

extern "C" void kernel_launch(void* const* d_in, const int* in_sizes, int n_in,
                              void* d_out, int out_size, void* d_ws, size_t ws_size,
                              hipStream_t stream)
{
    const float* x_paper  = (const float*)d_in[0];
    const float* x_author = (const float*)d_in[1];
    const int* src_pp = (const int*)d_in[2];
    const int* dst_pp = (const int*)d_in[3];
    const int* src_ap = (const int*)d_in[4];
    const int* dst_ap = (const int*)d_in[5];
    const int* src_pa = (const int*)d_in[6];
    const int* dst_pa = (const int*)d_in[7];
    const float* Wl1_pp = (const float*)d_in[8];
    const float* bl1_pp = (const float*)d_in[9];
    const float* Wr1_pp = (const float*)d_in[10];
    const float* Wl1_ap = (const float*)d_in[11];
    const float* bl1_ap = (const float*)d_in[12];
    const float* Wr1_ap = (const float*)d_in[13];
    const float* Wl1_pa = (const float*)d_in[14];
    const float* bl1_pa = (const float*)d_in[15];
    const float* Wr1_pa = (const float*)d_in[16];
    const float* Wl2_pp = (const float*)d_in[17];
    const float* bl2_pp = (const float*)d_in[18];
    const float* Wr2_pp = (const float*)d_in[19];
    const float* Wl2_ap = (const float*)d_in[20];
    const float* bl2_ap = (const float*)d_in[21];
    const float* Wr2_ap = (const float*)d_in[22];
    const float* W_lin  = (const float*)d_in[23];
    const float* b_lin  = (const float*)d_in[24];

    const int NP = in_sizes[0] / 64;
    const int NA = in_sizes[1] / 64;
    const int E_PP = in_sizes[2];
    const int E_AP = in_sizes[4];
    const int E_PA = in_sizes[6];

    const int nw_pp = (NP + PWIN - 1) >> PWBITS;   // 196
    const int nw_ap = nw_pp;                       // 196
    const int nw_pa = (NA + PWIN - 1) >> PWBITS;   // 98
    const int cap_pp = E_PP / nw_pp + CAPPAD;
    const int cap_ap = E_AP / nw_ap + CAPPAD;
    const int cap_pa = E_PA / nw_pa + CAPPAD;

    // ---- workspace ----
    char* wp = (char*)d_ws;
    int* wcur = (int*)wp;             wp += 768 * 4;   // 3 x 256, zeroed
    unsigned* bk_pp = (unsigned*)wp;  wp += (size_t)nw_pp * cap_pp * 4;
    unsigned* bk_ap = (unsigned*)wp;  wp += (size_t)nw_ap * cap_ap * 4;
    unsigned* bk_pa = (unsigned*)wp;  wp += (size_t)nw_pa * cap_pa * 4;
    int* csr_pp = (int*)wp;           wp += (size_t)nw_pp * cap_pp * 4;
    int* csr_ap = (int*)wp;           wp += (size_t)nw_ap * cap_ap * 4;
    int* csr_pa = (int*)wp;           wp += (size_t)nw_pa * cap_pa * 4;
    int* cnt    = (int*)wp;           wp += (size_t)(2 * NP + NA) * 4;
    int* rs     = (int*)wp;           wp += (size_t)(2 * NP + NA) * 4;
    ushort_t* h_pp = (ushort_t*)wp;   wp += (size_t)NP * 32 * 2;
    ushort_t* h_pa = (ushort_t*)wp;   wp += (size_t)NP * 32 * 2;
    ushort_t* h_ap = (ushort_t*)wp;   wp += (size_t)NA * 32 * 2;
    float* root_a = (float*)wp;       wp += (size_t)NA * 32 * 4;
    float* s_pp   = (float*)wp;       wp += (size_t)NP * 4;
    float* s_ap   = (float*)wp;       wp += (size_t)NA * 4;
    float* Wcomb_p = (float*)wp;      wp += 64 * 96 * 4;
    float* Wcomb_a = (float*)wp;      wp += 64 * 64 * 4;
    ushort_t* Wfrag_p = (ushort_t*)wp; wp += 12 * 64 * 8 * 2;
    ushort_t* Wfrag_a = (ushort_t*)wp; wp += 8 * 64 * 8 * 2;
    float* bias_p = (float*)wp;       wp += 32 * 4;
    float* bias_a = (float*)wp;       wp += 32 * 4;
    float* vv     = (float*)wp;       wp += 128 * 4;
    // root_p overlays the (dead after fill_win3) bucket region bk_pp..bk_ap
    float* root_p = (float*)bk_pp;    // NP*32*4 = 25.6MB <= bk_pp+bk_ap ~25.6MB

    int* cnt_pp = cnt,  * cnt_ap = cnt + NP,  * cnt_pa = cnt + 2 * NP;
    int* rs_pp  = rs,   * rs_ap  = rs + NP,   * rs_pa  = rs + 2 * NP;

    float* out = (float*)d_out;

    // zero the window cursors only
    hipMemsetAsync(wcur, 0, 768 * sizeof(int), stream);

    prep_weights<<<1, 256, 0, stream>>>(
        Wl1_pp, Wr1_pp, Wl1_ap, Wr1_ap, Wl1_pa, Wr1_pa,
        bl1_pp, bl1_ap, bl1_pa,
        Wl2_pp, bl2_pp, Wr2_pp, Wl2_ap, bl2_ap, Wr2_ap,
        W_lin, b_lin, Wcomb_p, Wcomb_a, Wfrag_p, Wfrag_a, bias_p, bias_a, vv);

    int nb_total = (E_PP + PCHUNK - 1) / PCHUNK + (E_AP + PCHUNK - 1) / PCHUNK
                 + (E_PA + PCHUNK - 1) / PCHUNK;
    partition3<<<nb_total, 256, 0, stream>>>(
        src_pp, dst_pp, E_PP, bk_pp, cap_pp, nw_pp, wcur + 0,
        src_ap, dst_ap, E_AP, bk_ap, cap_ap, nw_ap, wcur + 256,
        src_pa, dst_pa, E_PA, bk_pa, cap_pa, nw_pa, wcur + 512);

    fill_win3<<<nw_pp + nw_ap + nw_pa, 256, 0, stream>>>(
        bk_pp, wcur + 0,   cap_pp, csr_pp, cnt_pp, rs_pp, NP, nw_pp,
        bk_ap, wcur + 256, cap_ap, csr_ap, cnt_ap, rs_ap, NP, nw_ap,
        bk_pa, wcur + 512, cap_pa, csr_pa, cnt_pa, rs_pa, NA, nw_pa);

    proj_paper_mfma<<<(NP + 63) / 64, 256, 0, stream>>>(
        x_paper, Wfrag_p, bias_p, h_pp, h_pa, root_p, NP);
    proj_author_mfma<<<(NA + 63) / 64, 256, 0, stream>>>(
        x_author, Wfrag_a, bias_a, h_ap, root_a, NA);

    pull_paper<<<(NP + 63) / 64, 256, 0, stream>>>(
        h_pp, h_ap, root_p, csr_pp, rs_pp, cnt_pp, csr_ap, rs_ap, cnt_ap,
        vv, s_pp, out, NP);
    pull_author<<<(NA + 63) / 64, 256, 0, stream>>>(
        h_pa, root_a, csr_pa, rs_pa, cnt_pa, vv, s_ap, NA);

    pull2<<<((size_t)NP * 4 + 255) / 256, 256, 0, stream>>>(
        s_pp, s_ap, csr_pp, rs_pp, cnt_pp, csr_ap, rs_ap, cnt_ap, out, NP);
}

// Round 14
// 375.552 us; speedup vs baseline: 2.7302x; 1.1126x over previous
//
#include <hip/hip_runtime.h>

// ---------------------------------------------------------------------------
// HeteroSAGE: CSR pull; CSR built with ZERO per-edge global atomics.
//   partition3: 1564 blocks, register-staged edges (single stream read),
//               line-padded window cursors (no claim-atomic serialization).
//   fill_win3:  978 blocks (512-dst windows), register-staged bucket slice
//               (single bucket read): LDS hist -> scan -> cnt/rs -> csr.
//   proj via MFMA 16x16x32 bf16 (round-12)
//   pull: 4 lanes/node dwordx4 gathers (round-13) -> pull2 scalar layer-2.
// ---------------------------------------------------------------------------

typedef unsigned short ushort_t;
typedef __attribute__((ext_vector_type(8))) short bf16x8;
typedef __attribute__((ext_vector_type(4))) float f32x4;

#define PWBITS 9
#define PWIN   (1 << PWBITS)     // 512 dsts per window
#define PCHUNK 4096              // edges per partition block
#define CAPPAD 2048              // bucket slack (~22 sigma)
#define FW_R   12                // fill regs: 12 x uint4 = 12288 >= max cap

__device__ inline ushort_t f2bf(float f) {
    unsigned u = __float_as_uint(f);
    unsigned r = (u + 0x7FFFu + ((u >> 16) & 1u)) >> 16;
    return (ushort_t)r;
}
__device__ inline float bf2f_lo(unsigned u) { return __uint_as_float(u << 16); }
__device__ inline float bf2f_hi(unsigned u) { return __uint_as_float(u & 0xFFFF0000u); }
__device__ inline int ntl(const int* p) { return __builtin_nontemporal_load(p); }

__global__ void prep_weights(
    const float* __restrict__ Wl1_pp, const float* __restrict__ Wr1_pp,
    const float* __restrict__ Wl1_ap, const float* __restrict__ Wr1_ap,
    const float* __restrict__ Wl1_pa, const float* __restrict__ Wr1_pa,
    const float* __restrict__ bl1_pp, const float* __restrict__ bl1_ap,
    const float* __restrict__ bl1_pa,
    const float* __restrict__ Wl2_pp, const float* __restrict__ bl2_pp,
    const float* __restrict__ Wr2_pp,
    const float* __restrict__ Wl2_ap, const float* __restrict__ bl2_ap,
    const float* __restrict__ Wr2_ap,
    const float* __restrict__ W_lin, const float* __restrict__ b_lin,
    float* __restrict__ Wcomb_p,   // 64 x 96
    float* __restrict__ Wcomb_a,   // 64 x 64
    ushort_t* __restrict__ Wfrag_p, // 12 frags x 64 lanes x 8 bf16
    ushort_t* __restrict__ Wfrag_a, // 8 frags x 64 lanes x 8
    float* __restrict__ bias_p,
    float* __restrict__ bias_a,
    float* __restrict__ vv)
{
    int t = threadIdx.x;
    for (int idx = t; idx < 64 * 96; idx += 256) {
        int i = idx / 96, j = idx % 96;
        float v;
        if (j < 32)       v = Wl1_pp[i * 32 + j];
        else if (j < 64)  v = Wl1_pa[i * 32 + (j - 32)];
        else              v = Wr1_pp[i * 32 + (j - 64)] + Wr1_ap[i * 32 + (j - 64)];
        Wcomb_p[idx] = v;
    }
    for (int idx = t; idx < 64 * 64; idx += 256) {
        int i = idx / 64, j = idx % 64;
        Wcomb_a[idx] = (j < 32) ? Wl1_ap[i * 32 + j] : Wr1_pa[i * 32 + (j - 32)];
    }
    if (t < 32) {
        bias_p[t] = bl1_pp[t] + bl1_ap[t];
        bias_a[t] = bl1_pa[t];
        float vpp = 0.f, vr = 0.f, vap = 0.f;
        for (int j = 0; j < 32; ++j) {
            float wl = W_lin[j];
            vpp += Wl2_pp[t * 32 + j] * wl;
            vr  += (Wr2_pp[t * 32 + j] + Wr2_ap[t * 32 + j]) * wl;
            vap += Wl2_ap[t * 32 + j] * wl;
        }
        vv[t] = vpp; vv[32 + t] = vr; vv[96 + t] = vap;
    }
    if (t == 0) {
        float c = b_lin[0];
        for (int j = 0; j < 32; ++j) c += (bl2_pp[j] + bl2_ap[j]) * W_lin[j];
        vv[64] = c;
    }
    __syncthreads();
    for (int idx = t; idx < 12 * 64 * 8; idx += 256) {
        int f = idx >> 9, l = (idx >> 3) & 63, j = idx & 7;
        int nt = f >> 1, kh = f & 1;
        int k = kh * 32 + 8 * (l >> 4) + j;
        int n = nt * 16 + (l & 15);
        Wfrag_p[idx] = f2bf(Wcomb_p[k * 96 + n]);
    }
    for (int idx = t; idx < 8 * 64 * 8; idx += 256) {
        int f = idx >> 9, l = (idx >> 3) & 63, j = idx & 7;
        int nt = f >> 1, kh = f & 1;
        int k = kh * 32 + 8 * (l >> 4) + j;
        int n = nt * 16 + (l & 15);
        Wfrag_a[idx] = f2bf(Wcomb_a[k * 64 + n]);
    }
}

// one launch, all 3 relations. Register-staged edges (single stream read),
// LDS window counts, line-padded cursor claims, packed coalesced-ish writes.
// Packed word: (d_low9 << 18) | src  (src < 2^18).
__global__ __launch_bounds__(256)
void partition3(
    const int* __restrict__ src0, const int* __restrict__ dst0, int E0,
    unsigned* __restrict__ bk0, int cap0, int nw0, int* __restrict__ wc0,
    const int* __restrict__ src1, const int* __restrict__ dst1, int E1,
    unsigned* __restrict__ bk1, int cap1, int nw1, int* __restrict__ wc1,
    const int* __restrict__ src2, const int* __restrict__ dst2, int E2,
    unsigned* __restrict__ bk2, int cap2, int nw2, int* __restrict__ wc2)
{
    __shared__ int lcnt[PWIN];
    __shared__ int lbase[PWIN];
    int nb0 = (E0 + PCHUNK - 1) / PCHUNK;
    int nb1 = (E1 + PCHUNK - 1) / PCHUNK;
    int b = blockIdx.x;
    const int* src; const int* dst; int E; unsigned* bk; int cap; int nw; int* wc; int chunk;
    if (b < nb0)            { src = src0; dst = dst0; E = E0; bk = bk0; cap = cap0; nw = nw0; wc = wc0; chunk = b; }
    else if (b < nb0 + nb1) { src = src1; dst = dst1; E = E1; bk = bk1; cap = cap1; nw = nw1; wc = wc1; chunk = b - nb0; }
    else                    { src = src2; dst = dst2; E = E2; bk = bk2; cap = cap2; nw = nw2; wc = wc2; chunk = b - nb0 - nb1; }
    int e0 = chunk * PCHUNK;
    // stage 16 edges/thread (4 x int4), guarded tails
    int d_[16], s_[16];
#pragma unroll
    for (int r = 0; r < 4; ++r) {
        int base = e0 + r * 1024 + threadIdx.x * 4;
        if (base + 3 < E) {
            int4 dv = *(const int4*)(dst + base);
            int4 sv = *(const int4*)(src + base);
            d_[r * 4 + 0] = dv.x; d_[r * 4 + 1] = dv.y; d_[r * 4 + 2] = dv.z; d_[r * 4 + 3] = dv.w;
            s_[r * 4 + 0] = sv.x; s_[r * 4 + 1] = sv.y; s_[r * 4 + 2] = sv.z; s_[r * 4 + 3] = sv.w;
        } else {
#pragma unroll
            for (int k = 0; k < 4; ++k) {
                int e = base + k;
                d_[r * 4 + k] = (e < E) ? dst[e] : -1;
                s_[r * 4 + k] = 0;
            }
        }
    }
    for (int i = threadIdx.x; i < nw; i += 256) lcnt[i] = 0;
    __syncthreads();
#pragma unroll
    for (int k = 0; k < 16; ++k)
        if (d_[k] >= 0) atomicAdd(&lcnt[((unsigned)d_[k]) >> PWBITS], 1);
    __syncthreads();
    for (int i = threadIdx.x; i < nw; i += 256) {
        int c = lcnt[i];
        lbase[i] = (c > 0) ? atomicAdd(&wc[i * 16], c) : 0;   // 1 cursor / 64B line
        lcnt[i] = 0;
    }
    __syncthreads();
#pragma unroll
    for (int k = 0; k < 16; ++k) {
        int d = d_[k];
        if (d >= 0) {
            int w = ((unsigned)d) >> PWBITS;
            int off = lbase[w] + atomicAdd(&lcnt[w], 1);
            if (off < cap)
                bk[(size_t)w * cap + off] =
                    (((unsigned)(d & (PWIN - 1))) << 18) | (unsigned)s_[k];
        }
    }
}

// one 256-thread block per 512-dst window; bucket slice register-staged
// (single global read): LDS hist -> cnt -> exclusive scan -> rs -> csr.
__global__ __launch_bounds__(256)
void fill_win3(
    const unsigned* __restrict__ bk0, const int* __restrict__ wc0, int cap0,
    int* __restrict__ csr0, int* __restrict__ cnt0, int* __restrict__ rs0, int N0, int nw0,
    const unsigned* __restrict__ bk1, const int* __restrict__ wc1, int cap1,
    int* __restrict__ csr1, int* __restrict__ cnt1, int* __restrict__ rs1, int N1, int nw1,
    const unsigned* __restrict__ bk2, const int* __restrict__ wc2, int cap2,
    int* __restrict__ csr2, int* __restrict__ cnt2, int* __restrict__ rs2, int N2, int nw2)
{
    __shared__ int lc[PWIN];
    __shared__ int wsum[4], wpre[4];
    int b = blockIdx.x;
    const unsigned* bk; const int* wc; int cap; int* csr; int* cnt; int* rs; int N; int w;
    if (b < nw0)            { bk = bk0; wc = wc0; cap = cap0; csr = csr0; cnt = cnt0; rs = rs0; N = N0; w = b; }
    else if (b < nw0 + nw1) { bk = bk1; wc = wc1; cap = cap1; csr = csr1; cnt = cnt1; rs = rs1; N = N1; w = b - nw0; }
    else                    { bk = bk2; wc = wc2; cap = cap2; csr = csr2; cnt = cnt2; rs = rs2; N = N2; w = b - nw0 - nw1; }
    int d0 = w << PWBITS;
    int sz = wc[w * 16]; if (sz > cap) sz = cap;
    const unsigned* bkt = bk + (size_t)w * cap;
    // stage entries (uint4, sentinel-padded tails)
    uint4 u[FW_R];
#pragma unroll
    for (int r = 0; r < FW_R; ++r) {
        int i4 = r * 1024 + threadIdx.x * 4;
        if (i4 + 3 < sz) {
            u[r] = *(const uint4*)(bkt + i4);
        } else {
            u[r].x = (i4 + 0 < sz) ? bkt[i4 + 0] : 0xFFFFFFFFu;
            u[r].y = (i4 + 1 < sz) ? bkt[i4 + 1] : 0xFFFFFFFFu;
            u[r].z = (i4 + 2 < sz) ? bkt[i4 + 2] : 0xFFFFFFFFu;
            u[r].w = (i4 + 3 < sz) ? bkt[i4 + 3] : 0xFFFFFFFFu;
        }
    }
    for (int i = threadIdx.x; i < PWIN; i += 256) lc[i] = 0;
    __syncthreads();
#pragma unroll
    for (int r = 0; r < FW_R; ++r) {
        if (u[r].x != 0xFFFFFFFFu) atomicAdd(&lc[u[r].x >> 18], 1);
        if (u[r].y != 0xFFFFFFFFu) atomicAdd(&lc[u[r].y >> 18], 1);
        if (u[r].z != 0xFFFFFFFFu) atomicAdd(&lc[u[r].z >> 18], 1);
        if (u[r].w != 0xFFFFFFFFu) atomicAdd(&lc[u[r].w >> 18], 1);
    }
    __syncthreads();
    {   // cnt out (2 entries/thread)
        int i = threadIdx.x * 2;
        int d = d0 + i;
        if (d < N)     cnt[d] = lc[i];
        if (d + 1 < N) cnt[d + 1] = lc[i + 1];
    }
    // exclusive scan of lc[512], 2 elems/thread, base = w*cap
    int t2 = threadIdx.x * 2;
    int v0 = lc[t2], v1 = lc[t2 + 1];
    int ts = v0 + v1;
    int lane = threadIdx.x & 63;
    int wid = threadIdx.x >> 6;
    int incl = ts;
#pragma unroll
    for (int off = 1; off < 64; off <<= 1) {
        int o = __shfl_up(incl, off);
        if (lane >= off) incl += o;
    }
    if (lane == 63) wsum[wid] = incl;
    __syncthreads();
    if (threadIdx.x == 0) {
        int r = 0;
        for (int i = 0; i < 4; ++i) { wpre[i] = r; r += wsum[i]; }
    }
    __syncthreads();
    int run = w * cap + wpre[wid] + (incl - ts);
    lc[t2] = run;
    if (d0 + t2 < N) rs[d0 + t2] = run;
    run += v0;
    lc[t2 + 1] = run;
    if (d0 + t2 + 1 < N) rs[d0 + t2 + 1] = run;
    __syncthreads();
#pragma unroll
    for (int r = 0; r < FW_R; ++r) {
        if (u[r].x != 0xFFFFFFFFu) { int p = atomicAdd(&lc[u[r].x >> 18], 1); csr[p] = (int)(u[r].x & 0x3FFFFu); }
        if (u[r].y != 0xFFFFFFFFu) { int p = atomicAdd(&lc[u[r].y >> 18], 1); csr[p] = (int)(u[r].y & 0x3FFFFu); }
        if (u[r].z != 0xFFFFFFFFu) { int p = atomicAdd(&lc[u[r].z >> 18], 1); csr[p] = (int)(u[r].z & 0x3FFFFu); }
        if (u[r].w != 0xFFFFFFFFu) { int p = atomicAdd(&lc[u[r].w >> 18], 1); csr[p] = (int)(u[r].w & 0x3FFFFu); }
    }
}

__device__ inline bf16x8 cvt8(const float* p) {
    float4 a = *(const float4*)p;
    float4 b = *(const float4*)(p + 4);
    bf16x8 r;
    r[0] = (short)f2bf(a.x); r[1] = (short)f2bf(a.y);
    r[2] = (short)f2bf(a.z); r[3] = (short)f2bf(a.w);
    r[4] = (short)f2bf(b.x); r[5] = (short)f2bf(b.y);
    r[6] = (short)f2bf(b.z); r[7] = (short)f2bf(b.w);
    return r;
}

__global__ __launch_bounds__(256)
void proj_paper_mfma(const float* __restrict__ x, const ushort_t* __restrict__ Wfrag,
                     const float* __restrict__ bias,
                     ushort_t* __restrict__ h_pp, ushort_t* __restrict__ h_pa,
                     float* __restrict__ root_p, int N)
{
    int wave = threadIdx.x >> 6, lane = threadIdx.x & 63;
    int mbase = blockIdx.x * 64 + wave * 16;
    int row = lane & 15, grp = lane >> 4;
    int nA = mbase + row; if (nA > N - 1) nA = N - 1;
    const float* xr = x + (size_t)nA * 64 + grp * 8;
    bf16x8 a0 = cvt8(xr);
    bf16x8 a1 = cvt8(xr + 32);
    f32x4 acc0 = {0.f, 0.f, 0.f, 0.f}, acc1 = acc0, acc2 = acc0, acc3 = acc0;
    float bp0 = bias[row];
    float bp1 = bias[16 + row];
    f32x4 acc4 = {bp0, bp0, bp0, bp0};
    f32x4 acc5 = {bp1, bp1, bp1, bp1};
    const bf16x8* wf = (const bf16x8*)(Wfrag) + lane;
    acc0 = __builtin_amdgcn_mfma_f32_16x16x32_bf16(a0, wf[0 * 64], acc0, 0, 0, 0);
    acc0 = __builtin_amdgcn_mfma_f32_16x16x32_bf16(a1, wf[1 * 64], acc0, 0, 0, 0);
    acc1 = __builtin_amdgcn_mfma_f32_16x16x32_bf16(a0, wf[2 * 64], acc1, 0, 0, 0);
    acc1 = __builtin_amdgcn_mfma_f32_16x16x32_bf16(a1, wf[3 * 64], acc1, 0, 0, 0);
    acc2 = __builtin_amdgcn_mfma_f32_16x16x32_bf16(a0, wf[4 * 64], acc2, 0, 0, 0);
    acc2 = __builtin_amdgcn_mfma_f32_16x16x32_bf16(a1, wf[5 * 64], acc2, 0, 0, 0);
    acc3 = __builtin_amdgcn_mfma_f32_16x16x32_bf16(a0, wf[6 * 64], acc3, 0, 0, 0);
    acc3 = __builtin_amdgcn_mfma_f32_16x16x32_bf16(a1, wf[7 * 64], acc3, 0, 0, 0);
    acc4 = __builtin_amdgcn_mfma_f32_16x16x32_bf16(a0, wf[8 * 64], acc4, 0, 0, 0);
    acc4 = __builtin_amdgcn_mfma_f32_16x16x32_bf16(a1, wf[9 * 64], acc4, 0, 0, 0);
    acc5 = __builtin_amdgcn_mfma_f32_16x16x32_bf16(a0, wf[10 * 64], acc5, 0, 0, 0);
    acc5 = __builtin_amdgcn_mfma_f32_16x16x32_bf16(a1, wf[11 * 64], acc5, 0, 0, 0);
    int col = row;
    int node0 = mbase + grp * 4;
#pragma unroll
    for (int reg = 0; reg < 4; ++reg) {
        int nd = node0 + reg;
        if (nd < N) {
            size_t b32 = (size_t)nd * 32;
            h_pp[b32 + col]        = f2bf(acc0[reg]);
            h_pp[b32 + 16 + col]   = f2bf(acc1[reg]);
            h_pa[b32 + col]        = f2bf(acc2[reg]);
            h_pa[b32 + 16 + col]   = f2bf(acc3[reg]);
            root_p[b32 + col]      = acc4[reg];
            root_p[b32 + 16 + col] = acc5[reg];
        }
    }
}

__global__ __launch_bounds__(256)
void proj_author_mfma(const float* __restrict__ x, const ushort_t* __restrict__ Wfrag,
                      const float* __restrict__ bias,
                      ushort_t* __restrict__ h_ap, float* __restrict__ root_a, int N)
{
    int wave = threadIdx.x >> 6, lane = threadIdx.x & 63;
    int mbase = blockIdx.x * 64 + wave * 16;
    int row = lane & 15, grp = lane >> 4;
    int nA = mbase + row; if (nA > N - 1) nA = N - 1;
    const float* xr = x + (size_t)nA * 64 + grp * 8;
    bf16x8 a0 = cvt8(xr);
    bf16x8 a1 = cvt8(xr + 32);
    f32x4 acc0 = {0.f, 0.f, 0.f, 0.f}, acc1 = acc0;
    float bp0 = bias[row];
    float bp1 = bias[16 + row];
    f32x4 acc2 = {bp0, bp0, bp0, bp0};
    f32x4 acc3 = {bp1, bp1, bp1, bp1};
    const bf16x8* wf = (const bf16x8*)(Wfrag) + lane;
    acc0 = __builtin_amdgcn_mfma_f32_16x16x32_bf16(a0, wf[0 * 64], acc0, 0, 0, 0);
    acc0 = __builtin_amdgcn_mfma_f32_16x16x32_bf16(a1, wf[1 * 64], acc0, 0, 0, 0);
    acc1 = __builtin_amdgcn_mfma_f32_16x16x32_bf16(a0, wf[2 * 64], acc1, 0, 0, 0);
    acc1 = __builtin_amdgcn_mfma_f32_16x16x32_bf16(a1, wf[3 * 64], acc1, 0, 0, 0);
    acc2 = __builtin_amdgcn_mfma_f32_16x16x32_bf16(a0, wf[4 * 64], acc2, 0, 0, 0);
    acc2 = __builtin_amdgcn_mfma_f32_16x16x32_bf16(a1, wf[5 * 64], acc2, 0, 0, 0);
    acc3 = __builtin_amdgcn_mfma_f32_16x16x32_bf16(a0, wf[6 * 64], acc3, 0, 0, 0);
    acc3 = __builtin_amdgcn_mfma_f32_16x16x32_bf16(a1, wf[7 * 64], acc3, 0, 0, 0);
    int col = row;
    int node0 = mbase + grp * 4;
#pragma unroll
    for (int reg = 0; reg < 4; ++reg) {
        int nd = node0 + reg;
        if (nd < N) {
            size_t b32 = (size_t)nd * 32;
            h_ap[b32 + col]        = f2bf(acc0[reg]);
            h_ap[b32 + 16 + col]   = f2bf(acc1[reg]);
            root_a[b32 + col]      = acc2[reg];
            root_a[b32 + 16 + col] = acc3[reg];
        }
    }
}

#define ACC8(A, U) \
    A[0] += bf2f_lo((U).x); A[1] += bf2f_hi((U).x); \
    A[2] += bf2f_lo((U).y); A[3] += bf2f_hi((U).y); \
    A[4] += bf2f_lo((U).z); A[5] += bf2f_hi((U).z); \
    A[6] += bf2f_lo((U).w); A[7] += bf2f_hi((U).w);

__global__ __launch_bounds__(256, 8)
void pull_paper(const ushort_t* __restrict__ h_pp, const ushort_t* __restrict__ h_ap,
                const float* __restrict__ root,
                const int* __restrict__ csr_pp, const int* __restrict__ rs_pp,
                const int* __restrict__ cnt_pp,
                const int* __restrict__ csr_ap, const int* __restrict__ rs_ap,
                const int* __restrict__ cnt_ap,
                const float* __restrict__ vv,
                float* __restrict__ s_pp, float* __restrict__ out, int N)
{
    __shared__ float v0[32], v1[32];
    __shared__ float c2s;
    if (threadIdx.x < 32) { v0[threadIdx.x] = vv[threadIdx.x]; v1[threadIdx.x] = vv[32 + threadIdx.x]; }
    if (threadIdx.x == 0) c2s = vv[64];
    __syncthreads();
    int n = blockIdx.x * 64 + (threadIdx.x >> 2);
    if (n >= N) return;
    int c = threadIdx.x & 3;
    float a[8];
#pragma unroll
    for (int k = 0; k < 8; ++k) a[k] = 0.f;
    int s1 = rs_pp[n], k1 = cnt_pp[n], e1 = s1 + k1;
    int j = s1;
    for (; j + 4 <= e1; j += 4) {
        int i0 = ntl(csr_pp + j), i1 = ntl(csr_pp + j + 1);
        int i2 = ntl(csr_pp + j + 2), i3 = ntl(csr_pp + j + 3);
        uint4 u0 = ((const uint4*)(h_pp + (size_t)i0 * 32))[c];
        uint4 u1 = ((const uint4*)(h_pp + (size_t)i1 * 32))[c];
        uint4 u2 = ((const uint4*)(h_pp + (size_t)i2 * 32))[c];
        uint4 u3 = ((const uint4*)(h_pp + (size_t)i3 * 32))[c];
        ACC8(a, u0) ACC8(a, u1) ACC8(a, u2) ACC8(a, u3)
    }
    for (; j < e1; ++j) {
        uint4 u0 = ((const uint4*)(h_pp + (size_t)ntl(csr_pp + j) * 32))[c];
        ACC8(a, u0)
    }
    float b[8];
#pragma unroll
    for (int k = 0; k < 8; ++k) b[k] = 0.f;
    int s2 = rs_ap[n], k2 = cnt_ap[n], e2 = s2 + k2;
    j = s2;
    for (; j + 4 <= e2; j += 4) {
        int i0 = ntl(csr_ap + j), i1 = ntl(csr_ap + j + 1);
        int i2 = ntl(csr_ap + j + 2), i3 = ntl(csr_ap + j + 3);
        uint4 u0 = ((const uint4*)(h_ap + (size_t)i0 * 32))[c];
        uint4 u1 = ((const uint4*)(h_ap + (size_t)i1 * 32))[c];
        uint4 u2 = ((const uint4*)(h_ap + (size_t)i2 * 32))[c];
        uint4 u3 = ((const uint4*)(h_ap + (size_t)i3 * 32))[c];
        ACC8(b, u0) ACC8(b, u1) ACC8(b, u2) ACC8(b, u3)
    }
    for (; j < e2; ++j) {
        uint4 u0 = ((const uint4*)(h_ap + (size_t)ntl(csr_ap + j) * 32))[c];
        ACC8(b, u0)
    }
    float ipp = 1.0f / fmaxf((float)k1, 1.0f);
    float iap = 1.0f / fmaxf((float)k2, 1.0f);
    const float* rt = root + (size_t)n * 32 + 8 * c;
    float d0 = 0.f, d1 = 0.f;
#pragma unroll
    for (int k = 0; k < 8; ++k) {
        float p = fmaxf(rt[k] + a[k] * ipp + b[k] * iap, 0.f);
        d0 += p * v0[8 * c + k];
        d1 += p * v1[8 * c + k];
    }
    d0 += __shfl_xor(d0, 1); d0 += __shfl_xor(d0, 2);
    d1 += __shfl_xor(d1, 1); d1 += __shfl_xor(d1, 2);
    if (c == 0) { s_pp[n] = d0; out[n] = d1 + c2s; }
}

__global__ __launch_bounds__(256, 8)
void pull_author(const ushort_t* __restrict__ h_pa, const float* __restrict__ root,
                 const int* __restrict__ csr_pa, const int* __restrict__ rs_pa,
                 const int* __restrict__ cnt_pa,
                 const float* __restrict__ vv, float* __restrict__ s_ap, int N)
{
    __shared__ float v0[32];
    if (threadIdx.x < 32) v0[threadIdx.x] = vv[96 + threadIdx.x];
    __syncthreads();
    int n = blockIdx.x * 64 + (threadIdx.x >> 2);
    if (n >= N) return;
    int c = threadIdx.x & 3;
    float a[8];
#pragma unroll
    for (int k = 0; k < 8; ++k) a[k] = 0.f;
    int s1 = rs_pa[n], k1 = cnt_pa[n], e1 = s1 + k1;
    int j = s1;
    for (; j + 4 <= e1; j += 4) {
        int i0 = ntl(csr_pa + j), i1 = ntl(csr_pa + j + 1);
        int i2 = ntl(csr_pa + j + 2), i3 = ntl(csr_pa + j + 3);
        uint4 u0 = ((const uint4*)(h_pa + (size_t)i0 * 32))[c];
        uint4 u1 = ((const uint4*)(h_pa + (size_t)i1 * 32))[c];
        uint4 u2 = ((const uint4*)(h_pa + (size_t)i2 * 32))[c];
        uint4 u3 = ((const uint4*)(h_pa + (size_t)i3 * 32))[c];
        ACC8(a, u0) ACC8(a, u1) ACC8(a, u2) ACC8(a, u3)
    }
    for (; j < e1; ++j) {
        uint4 u0 = ((const uint4*)(h_pa + (size_t)ntl(csr_pa + j) * 32))[c];
        ACC8(a, u0)
    }
    float ip = 1.0f / fmaxf((float)k1, 1.0f);
    const float* rt = root + (size_t)n * 32 + 8 * c;
    float d0 = 0.f;
#pragma unroll
    for (int k = 0; k < 8; ++k) {
        float p = fmaxf(rt[k] + a[k] * ip, 0.f);
        d0 += p * v0[8 * c + k];
    }
    d0 += __shfl_xor(d0, 1); d0 += __shfl_xor(d0, 2);
    if (c == 0) s_ap[n] = d0;
}

__global__ __launch_bounds__(256, 8)
void pull2(const float* __restrict__ s_pp, const float* __restrict__ s_ap,
           const int* __restrict__ csr_pp, const int* __restrict__ rs_pp,
           const int* __restrict__ cnt_pp,
           const int* __restrict__ csr_ap, const int* __restrict__ rs_ap,
           const int* __restrict__ cnt_ap,
           float* __restrict__ out, int N)
{
    int g = (blockIdx.x * blockDim.x + threadIdx.x) >> 2;
    int c = threadIdx.x & 3;
    if (g >= N) return;
    int s1 = rs_pp[g], k1 = cnt_pp[g], e1 = s1 + k1;
    float t = 0.f;
    for (int j = s1 + c; j < e1; j += 4) t += s_pp[ntl(csr_pp + j)];
    int s2 = rs_ap[g], k2 = cnt_ap[g], e2 = s2 + k2;
    float u = 0.f;
    for (int j = s2 + c; j < e2; j += 4) u += s_ap[ntl(csr_ap + j)];
    t += __shfl_xor(t, 1); t += __shfl_xor(t, 2);
    u += __shfl_xor(u, 1); u += __shfl_xor(u, 2);
    if (c == 0) {
        out[g] += t / fmaxf((float)k1, 1.f) + u / fmaxf((float)k2, 1.f);
    }
}

extern "C" void kernel_launch(void* const* d_in, const int* in_sizes, int n_in,
                              void* d_out, int out_size, void* d_ws, size_t ws_size,
                              hipStream_t stream)
{
    const float* x_paper  = (const float*)d_in[0];
    const float* x_author = (const float*)d_in[1];
    const int* src_pp = (const int*)d_in[2];
    const int* dst_pp = (const int*)d_in[3];
    const int* src_ap = (const int*)d_in[4];
    const int* dst_ap = (const int*)d_in[5];
    const int* src_pa = (const int*)d_in[6];
    const int* dst_pa = (const int*)d_in[7];
    const float* Wl1_pp = (const float*)d_in[8];
    const float* bl1_pp = (const float*)d_in[9];
    const float* Wr1_pp = (const float*)d_in[10];
    const float* Wl1_ap = (const float*)d_in[11];
    const float* bl1_ap = (const float*)d_in[12];
    const float* Wr1_ap = (const float*)d_in[13];
    const float* Wl1_pa = (const float*)d_in[14];
    const float* bl1_pa = (const float*)d_in[15];
    const float* Wr1_pa = (const float*)d_in[16];
    const float* Wl2_pp = (const float*)d_in[17];
    const float* bl2_pp = (const float*)d_in[18];
    const float* Wr2_pp = (const float*)d_in[19];
    const float* Wl2_ap = (const float*)d_in[20];
    const float* bl2_ap = (const float*)d_in[21];
    const float* Wr2_ap = (const float*)d_in[22];
    const float* W_lin  = (const float*)d_in[23];
    const float* b_lin  = (const float*)d_in[24];

    const int NP = in_sizes[0] / 64;
    const int NA = in_sizes[1] / 64;
    const int E_PP = in_sizes[2];
    const int E_AP = in_sizes[4];
    const int E_PA = in_sizes[6];

    const int nw_pp = (NP + PWIN - 1) >> PWBITS;   // 391
    const int nw_ap = nw_pp;                       // 391
    const int nw_pa = (NA + PWIN - 1) >> PWBITS;   // 196
    const int cap_pp = ((E_PP / nw_pp + CAPPAD) + 3) & ~3;
    const int cap_ap = ((E_AP / nw_ap + CAPPAD) + 3) & ~3;
    const int cap_pa = ((E_PA / nw_pa + CAPPAD) + 3) & ~3;

    // ---- workspace ----
    char* wp = (char*)d_ws;
    int* wcur = (int*)wp;             wp += (size_t)3 * PWIN * 16 * 4;  // line-padded cursors
    unsigned* bk_pp = (unsigned*)wp;  wp += (size_t)nw_pp * cap_pp * 4;
    unsigned* bk_ap = (unsigned*)wp;  wp += (size_t)nw_ap * cap_ap * 4;
    unsigned* bk_pa = (unsigned*)wp;  wp += (size_t)nw_pa * cap_pa * 4;
    int* csr_pp = (int*)wp;           wp += (size_t)nw_pp * cap_pp * 4;
    int* csr_ap = (int*)wp;           wp += (size_t)nw_ap * cap_ap * 4;
    int* csr_pa = (int*)wp;           wp += (size_t)nw_pa * cap_pa * 4;
    int* cnt    = (int*)wp;           wp += (size_t)(2 * NP + NA) * 4;
    int* rs     = (int*)wp;           wp += (size_t)(2 * NP + NA) * 4;
    ushort_t* h_pp = (ushort_t*)wp;   wp += (size_t)NP * 32 * 2;
    ushort_t* h_pa = (ushort_t*)wp;   wp += (size_t)NP * 32 * 2;
    ushort_t* h_ap = (ushort_t*)wp;   wp += (size_t)NA * 32 * 2;
    float* root_a = (float*)wp;       wp += (size_t)NA * 32 * 4;
    float* s_pp   = (float*)wp;       wp += (size_t)NP * 4;
    float* s_ap   = (float*)wp;       wp += (size_t)NA * 4;
    float* Wcomb_p = (float*)wp;      wp += 64 * 96 * 4;
    float* Wcomb_a = (float*)wp;      wp += 64 * 64 * 4;
    ushort_t* Wfrag_p = (ushort_t*)wp; wp += 12 * 64 * 8 * 2;
    ushort_t* Wfrag_a = (ushort_t*)wp; wp += 8 * 64 * 8 * 2;
    float* bias_p = (float*)wp;       wp += 32 * 4;
    float* bias_a = (float*)wp;       wp += 32 * 4;
    float* vv     = (float*)wp;       wp += 128 * 4;
    // root_p overlays the (dead after fill_win3) bucket region (33.6MB >= 25.6MB)
    float* root_p = (float*)bk_pp;

    int* cnt_pp = cnt,  * cnt_ap = cnt + NP,  * cnt_pa = cnt + 2 * NP;
    int* rs_pp  = rs,   * rs_ap  = rs + NP,   * rs_pa  = rs + 2 * NP;

    float* out = (float*)d_out;

    // zero the (line-padded) window cursors
    hipMemsetAsync(wcur, 0, (size_t)3 * PWIN * 16 * 4, stream);

    prep_weights<<<1, 256, 0, stream>>>(
        Wl1_pp, Wr1_pp, Wl1_ap, Wr1_ap, Wl1_pa, Wr1_pa,
        bl1_pp, bl1_ap, bl1_pa,
        Wl2_pp, bl2_pp, Wr2_pp, Wl2_ap, bl2_ap, Wr2_ap,
        W_lin, b_lin, Wcomb_p, Wcomb_a, Wfrag_p, Wfrag_a, bias_p, bias_a, vv);

    int nb_total = (E_PP + PCHUNK - 1) / PCHUNK + (E_AP + PCHUNK - 1) / PCHUNK
                 + (E_PA + PCHUNK - 1) / PCHUNK;
    partition3<<<nb_total, 256, 0, stream>>>(
        src_pp, dst_pp, E_PP, bk_pp, cap_pp, nw_pp, wcur + 0,
        src_ap, dst_ap, E_AP, bk_ap, cap_ap, nw_ap, wcur + PWIN * 16,
        src_pa, dst_pa, E_PA, bk_pa, cap_pa, nw_pa, wcur + 2 * PWIN * 16);

    fill_win3<<<nw_pp + nw_ap + nw_pa, 256, 0, stream>>>(
        bk_pp, wcur + 0,            cap_pp, csr_pp, cnt_pp, rs_pp, NP, nw_pp,
        bk_ap, wcur + PWIN * 16,    cap_ap, csr_ap, cnt_ap, rs_ap, NP, nw_ap,
        bk_pa, wcur + 2 * PWIN * 16, cap_pa, csr_pa, cnt_pa, rs_pa, NA, nw_pa);

    proj_paper_mfma<<<(NP + 63) / 64, 256, 0, stream>>>(
        x_paper, Wfrag_p, bias_p, h_pp, h_pa, root_p, NP);
    proj_author_mfma<<<(NA + 63) / 64, 256, 0, stream>>>(
        x_author, Wfrag_a, bias_a, h_ap, root_a, NA);

    pull_paper<<<(NP + 63) / 64, 256, 0, stream>>>(
        h_pp, h_ap, root_p, csr_pp, rs_pp, cnt_pp, csr_ap, rs_ap, cnt_ap,
        vv, s_pp, out, NP);
    pull_author<<<(NA + 63) / 64, 256, 0, stream>>>(
        h_pa, root_a, csr_pa, rs_pa, cnt_pa, vv, s_ap, NA);

    pull2<<<((size_t)NP * 4 + 255) / 256, 256, 0, stream>>>(
        s_pp, s_ap, csr_pp, rs_pp, cnt_pp, csr_ap, rs_ap, cnt_ap, out, NP);
}